// Round 1
// baseline (6716.960 us; speedup 1.0000x reference)
//
#include <hip/hip_runtime.h>
#include <math.h>

#define NN 100000
#define KHID 128
#define KCLS 40
#define LN_EPS 1e-5f

// ---------------- degree / norm ----------------
__global__ __launch_bounds__(256) void k_init_deg(float* __restrict__ deg) {
    int i = blockIdx.x * 256 + threadIdx.x;
    if (i < NN) deg[i] = 1.0f;   // self-loop contributes 1
}

__global__ __launch_bounds__(256) void k_degree(const int* __restrict__ dst,
                                                float* __restrict__ deg, int E) {
    int e = blockIdx.x * 256 + threadIdx.x;
    if (e < E) atomicAdd(&deg[dst[e]], 1.0f);
}

__global__ __launch_bounds__(256) void k_rsqrt(float* __restrict__ deg) {
    int i = blockIdx.x * 256 + threadIdx.x;
    if (i < NN) deg[i] = rsqrtf(deg[i]);
}

// ---------------- GEMM: C[N,Kout] = X[N,Kin] @ W[Kin,Kout] ----------------
#define TM 64
#define TN 64
#define TK 32

__global__ __launch_bounds__(256) void k_gemm(const float* __restrict__ X,
                                              const float* __restrict__ W,
                                              float* __restrict__ C,
                                              int Nrows, int Kin, int Kout) {
    __shared__ float Xs[TK][TM + 4];   // transposed: Xs[k][m]; +4 keeps float4 align, breaks conflicts
    __shared__ float Ws[TK][TN];       // Ws[k][n]

    int tid  = threadIdx.x;
    int row0 = blockIdx.x * TM;
    int col0 = blockIdx.y * TN;
    int tr = tid >> 4;        // 0..15
    int tc = tid & 15;        // 0..15

    float acc[4][4];
#pragma unroll
    for (int i = 0; i < 4; i++)
#pragma unroll
        for (int j = 0; j < 4; j++) acc[i][j] = 0.f;

    for (int k0 = 0; k0 < Kin; k0 += TK) {
        // X tile: 64 rows x 32 k, each thread loads 8 consecutive k of one row
        {
            int r  = tid >> 2;          // 0..63
            int kk = (tid & 3) * 8;     // 0,8,16,24
            int grow = row0 + r;
            float xv[8];
            if (grow < Nrows) {
                const float* xp = X + (size_t)grow * Kin + k0 + kk;
                float4 a = *(const float4*)xp;
                float4 b = *(const float4*)(xp + 4);
                xv[0]=a.x; xv[1]=a.y; xv[2]=a.z; xv[3]=a.w;
                xv[4]=b.x; xv[5]=b.y; xv[6]=b.z; xv[7]=b.w;
            } else {
#pragma unroll
                for (int i = 0; i < 8; i++) xv[i] = 0.f;
            }
#pragma unroll
            for (int i = 0; i < 8; i++) Xs[kk + i][r] = xv[i];
        }
        // W tile: 32 k x 64 n, each thread loads 8 consecutive n of one k
        {
            int kw = tid >> 3;          // 0..31
            int n  = (tid & 7) * 8;     // 0..56
            const float* wp = W + (size_t)(k0 + kw) * Kout + col0 + n;
#pragma unroll
            for (int j = 0; j < 8; j++) {
                int col = col0 + n + j;
                Ws[kw][n + j] = (col < Kout) ? wp[j] : 0.f;
            }
        }
        __syncthreads();
#pragma unroll
        for (int k = 0; k < TK; k++) {
            float4 xv4 = *(const float4*)&Xs[k][tr * 4];
            float4 wv4 = *(const float4*)&Ws[k][tc * 4];
            acc[0][0] += xv4.x * wv4.x; acc[0][1] += xv4.x * wv4.y;
            acc[0][2] += xv4.x * wv4.z; acc[0][3] += xv4.x * wv4.w;
            acc[1][0] += xv4.y * wv4.x; acc[1][1] += xv4.y * wv4.y;
            acc[1][2] += xv4.y * wv4.z; acc[1][3] += xv4.y * wv4.w;
            acc[2][0] += xv4.z * wv4.x; acc[2][1] += xv4.z * wv4.y;
            acc[2][2] += xv4.z * wv4.z; acc[2][3] += xv4.z * wv4.w;
            acc[3][0] += xv4.w * wv4.x; acc[3][1] += xv4.w * wv4.y;
            acc[3][2] += xv4.w * wv4.z; acc[3][3] += xv4.w * wv4.w;
        }
        __syncthreads();
    }
#pragma unroll
    for (int i = 0; i < 4; i++) {
        int grow = row0 + tr * 4 + i;
        if (grow >= Nrows) continue;
#pragma unroll
        for (int j = 0; j < 4; j++) {
            int col = col0 + tc * 4 + j;
            if (col < Kout) C[(size_t)grow * Kout + col] = acc[i][j];
        }
    }
}

// ---------------- self-loop init: agg[i,:] = dinv[i]^2 * h[i,:] ----------------
template <int K>
__global__ __launch_bounds__(256) void k_selfloop(const float* __restrict__ h,
                                                  const float* __restrict__ dinv,
                                                  float* __restrict__ agg) {
    size_t idx = (size_t)blockIdx.x * 256 + threadIdx.x;
    if (idx < (size_t)NN * K) {
        int i = (int)(idx / K);
        float v = dinv[i];
        agg[idx] = v * v * h[idx];
    }
}

// ---------------- edge scatter, width 128: 32 lanes/edge, float4 ----------------
__global__ __launch_bounds__(256) void k_scatter128(const float* __restrict__ h,
                                                    float* __restrict__ agg,
                                                    const int* __restrict__ src,
                                                    const int* __restrict__ dst,
                                                    const float* __restrict__ dinv, int E) {
    int t = blockIdx.x * 256 + threadIdx.x;
    int e = t >> 5;
    if (e >= E) return;
    int lane = t & 31;
    int s = src[e], d = dst[e];
    float w = dinv[s] * dinv[d];
    float4 v = *(const float4*)(h + (size_t)s * 128 + lane * 4);
    float* ap = agg + (size_t)d * 128 + lane * 4;
    atomicAdd(ap + 0, w * v.x);
    atomicAdd(ap + 1, w * v.y);
    atomicAdd(ap + 2, w * v.z);
    atomicAdd(ap + 3, w * v.w);
}

// ---------------- edge scatter, width 40: 16 lanes/edge (10 active) ----------------
__global__ __launch_bounds__(256) void k_scatter40(const float* __restrict__ h,
                                                   float* __restrict__ agg,
                                                   const int* __restrict__ src,
                                                   const int* __restrict__ dst,
                                                   const float* __restrict__ dinv, int E) {
    int t = blockIdx.x * 256 + threadIdx.x;
    int e = t >> 4;
    if (e >= E) return;
    int lane = t & 15;
    if (lane >= 10) return;
    int s = src[e], d = dst[e];
    float w = dinv[s] * dinv[d];
    float4 v = *(const float4*)(h + (size_t)s * 40 + lane * 4);
    float* ap = agg + (size_t)d * 40 + lane * 4;
    atomicAdd(ap + 0, w * v.x);
    atomicAdd(ap + 1, w * v.y);
    atomicAdd(ap + 2, w * v.z);
    atomicAdd(ap + 3, w * v.w);
}

// ---------------- LN + ReLU, K=128, one wave per node ----------------
__global__ __launch_bounds__(256) void k_ln_relu(const float* __restrict__ agg,
                                                 const float* __restrict__ bias,
                                                 const float* __restrict__ gamma,
                                                 const float* __restrict__ beta,
                                                 float* __restrict__ out) {
    int wave = threadIdx.x >> 6;
    int lane = threadIdx.x & 63;
    int i = blockIdx.x * 4 + wave;
    if (i >= NN) return;
    float2 v2 = *(const float2*)(agg + (size_t)i * 128 + lane * 2);
    float2 bb = *(const float2*)(bias + lane * 2);
    float x0 = v2.x + bb.x, x1 = v2.y + bb.y;
    float s = x0 + x1;
#pragma unroll
    for (int m = 1; m < 64; m <<= 1) s += __shfl_xor(s, m);
    float mu = s * (1.f / 128.f);
    float d0 = x0 - mu, d1 = x1 - mu;
    float vs = d0 * d0 + d1 * d1;
#pragma unroll
    for (int m = 1; m < 64; m <<= 1) vs += __shfl_xor(vs, m);
    float inv = rsqrtf(vs * (1.f / 128.f) + LN_EPS);
    float2 gg = *(const float2*)(gamma + lane * 2);
    float2 ee = *(const float2*)(beta + lane * 2);
    float o0 = fmaxf(d0 * inv * gg.x + ee.x, 0.f);
    float o1 = fmaxf(d1 * inv * gg.y + ee.y, 0.f);
    *(float2*)(out + (size_t)i * 128 + lane * 2) = make_float2(o0, o1);
}

// ---------------- bias + log_softmax over 40 classes, one wave per node ----------------
__global__ __launch_bounds__(256) void k_logsoftmax(const float* __restrict__ agg,
                                                    const float* __restrict__ b3,
                                                    float* __restrict__ out) {
    int wave = threadIdx.x >> 6;
    int lane = threadIdx.x & 63;
    int i = blockIdx.x * 4 + wave;
    if (i >= NN) return;
    float v = (lane < KCLS) ? agg[(size_t)i * KCLS + lane] + b3[lane] : -INFINITY;
    float m = v;
#pragma unroll
    for (int msk = 1; msk < 64; msk <<= 1) m = fmaxf(m, __shfl_xor(m, msk));
    float ex = (lane < KCLS) ? expf(v - m) : 0.f;
    float s = ex;
#pragma unroll
    for (int msk = 1; msk < 64; msk <<= 1) s += __shfl_xor(s, msk);
    float ls = v - m - logf(s);
    if (lane < KCLS) out[(size_t)i * KCLS + lane] = ls;
}

extern "C" void kernel_launch(void* const* d_in, const int* in_sizes, int n_in,
                              void* d_out, int out_size, void* d_ws, size_t ws_size,
                              hipStream_t stream) {
    const float* x   = (const float*)d_in[0];
    const int*   ei  = (const int*)d_in[1];
    const float* W1  = (const float*)d_in[2];
    const float* b1  = (const float*)d_in[3];
    const float* g1  = (const float*)d_in[4];
    const float* be1 = (const float*)d_in[5];
    const float* W2  = (const float*)d_in[6];
    const float* b2  = (const float*)d_in[7];
    const float* g2  = (const float*)d_in[8];
    const float* be2 = (const float*)d_in[9];
    const float* W3  = (const float*)d_in[10];
    const float* b3  = (const float*)d_in[11];
    const int E = in_sizes[1] / 2;
    const int* srcI = ei;        // edge_index[0] = message sources
    const int* dstI = ei + E;    // edge_index[1] = aggregation targets

    float* ws   = (float*)d_ws;
    float* dinv = ws;                                  // [NN]
    float* bufA = ws + NN;                             // [NN*128]
    float* bufB = bufA + (size_t)NN * 128;             // [NN*128]
    float* out  = (float*)d_out;

    // ---- norm ----
    k_init_deg<<<(NN + 255) / 256, 256, 0, stream>>>(dinv);
    k_degree<<<(E + 255) / 256, 256, 0, stream>>>(dstI, dinv, E);
    k_rsqrt<<<(NN + 255) / 256, 256, 0, stream>>>(dinv);

    const int gx = (NN + TM - 1) / TM;
    dim3 blk(256);

    // ---- layer 1: x @ W1 -> bufA; agg -> bufB; LN/ReLU -> bufA ----
    {
        dim3 grid(gx, (KHID + TN - 1) / TN);
        k_gemm<<<grid, blk, 0, stream>>>(x, W1, bufA, NN, KHID, KHID);
    }
    k_selfloop<128><<<((size_t)NN * 128 + 255) / 256, blk, 0, stream>>>(bufA, dinv, bufB);
    k_scatter128<<<((size_t)E * 32 + 255) / 256, blk, 0, stream>>>(bufA, bufB, srcI, dstI, dinv, E);
    k_ln_relu<<<(NN + 3) / 4, blk, 0, stream>>>(bufB, b1, g1, be1, bufA);

    // ---- layer 2: bufA @ W2 -> bufB; agg -> bufA; LN/ReLU -> bufB ----
    {
        dim3 grid(gx, (KHID + TN - 1) / TN);
        k_gemm<<<grid, blk, 0, stream>>>(bufA, W2, bufB, NN, KHID, KHID);
    }
    k_selfloop<128><<<((size_t)NN * 128 + 255) / 256, blk, 0, stream>>>(bufB, dinv, bufA);
    k_scatter128<<<((size_t)E * 32 + 255) / 256, blk, 0, stream>>>(bufB, bufA, srcI, dstI, dinv, E);
    k_ln_relu<<<(NN + 3) / 4, blk, 0, stream>>>(bufA, b2, g2, be2, bufB);

    // ---- layer 3: bufB @ W3 -> h3 (bufA); agg3 (bufA + NN*64); log_softmax -> out ----
    float* h3   = bufA;
    float* agg3 = bufA + (size_t)NN * 64;
    {
        dim3 grid(gx, (KCLS + TN - 1) / TN);
        k_gemm<<<grid, blk, 0, stream>>>(bufB, W3, h3, NN, KHID, KCLS);
    }
    k_selfloop<40><<<((size_t)NN * 40 + 255) / 256, blk, 0, stream>>>(h3, dinv, agg3);
    k_scatter40<<<((size_t)E * 16 + 255) / 256, blk, 0, stream>>>(h3, agg3, srcI, dstI, dinv, E);
    k_logsoftmax<<<(NN + 3) / 4, blk, 0, stream>>>(agg3, b3, out);
}

// Round 2
// 1043.928 us; speedup vs baseline: 6.4343x; 6.4343x over previous
//
#include <hip/hip_runtime.h>
#include <math.h>

#define NN 100000
#define KHID 128
#define KCLS 40
#define LN_EPS 1e-5f

// ======================= CSR build =======================
__global__ __launch_bounds__(256) void k_zero_int(int* __restrict__ p, int n) {
    int i = blockIdx.x * 256 + threadIdx.x;
    if (i < n) p[i] = 0;
}

__global__ __launch_bounds__(256) void k_count(const int* __restrict__ dst,
                                               int* __restrict__ cnt, int E) {
    int e = blockIdx.x * 256 + threadIdx.x;
    if (e < E) atomicAdd(&cnt[dst[e]], 1);
}

__global__ __launch_bounds__(256) void k_dinv(const int* __restrict__ cnt,
                                              float* __restrict__ dinv) {
    int i = blockIdx.x * 256 + threadIdx.x;
    if (i < NN) dinv[i] = rsqrtf((float)(1 + cnt[i]));   // +1 self-loop
}

// single-workgroup exclusive scan of cnt[NN] -> rowptr[NN]
__global__ __launch_bounds__(1024) void k_scan(const int* __restrict__ cnt,
                                               int* __restrict__ rowptr) {
    __shared__ int part[1024];
    const int chunk = (NN + 1023) / 1024;
    int t = threadIdx.x;
    int lo = t * chunk, hi = min(lo + chunk, NN);
    int s = 0;
    for (int i = lo; i < hi; i++) s += cnt[i];
    part[t] = s;
    __syncthreads();
    for (int off = 1; off < 1024; off <<= 1) {
        int u = (t >= off) ? part[t - off] : 0;
        __syncthreads();
        part[t] += u;
        __syncthreads();
    }
    int run = (t == 0) ? 0 : part[t - 1];   // exclusive prefix for this chunk
    for (int i = lo; i < hi; i++) {
        rowptr[i] = run;
        run += cnt[i];
    }
}

// fill: rowptr becomes "end" pointers; start_i = rowptr[i-1] afterwards
__global__ __launch_bounds__(256) void k_fill(const int* __restrict__ src,
                                              const int* __restrict__ dst,
                                              int* __restrict__ rowptr,
                                              int* __restrict__ col, int E) {
    int e = blockIdx.x * 256 + threadIdx.x;
    if (e < E) {
        int pos = atomicAdd(&rowptr[dst[e]], 1);
        col[pos] = src[e];
    }
}

// ======================= GEMM =======================
#define TM 64
#define TN 64
#define TK 32

__global__ __launch_bounds__(256) void k_gemm(const float* __restrict__ X,
                                              const float* __restrict__ W,
                                              float* __restrict__ C,
                                              int Nrows, int Kin, int Kout) {
    __shared__ float Xs[TK][TM + 4];
    __shared__ float Ws[TK][TN];

    int tid  = threadIdx.x;
    int row0 = blockIdx.x * TM;
    int col0 = blockIdx.y * TN;
    int tr = tid >> 4;
    int tc = tid & 15;

    float acc[4][4];
#pragma unroll
    for (int i = 0; i < 4; i++)
#pragma unroll
        for (int j = 0; j < 4; j++) acc[i][j] = 0.f;

    for (int k0 = 0; k0 < Kin; k0 += TK) {
        {
            int r  = tid >> 2;
            int kk = (tid & 3) * 8;
            int grow = row0 + r;
            float xv[8];
            if (grow < Nrows) {
                const float* xp = X + (size_t)grow * Kin + k0 + kk;
                float4 a = *(const float4*)xp;
                float4 b = *(const float4*)(xp + 4);
                xv[0]=a.x; xv[1]=a.y; xv[2]=a.z; xv[3]=a.w;
                xv[4]=b.x; xv[5]=b.y; xv[6]=b.z; xv[7]=b.w;
            } else {
#pragma unroll
                for (int i = 0; i < 8; i++) xv[i] = 0.f;
            }
#pragma unroll
            for (int i = 0; i < 8; i++) Xs[kk + i][r] = xv[i];
        }
        {
            int kw = tid >> 3;
            int n  = (tid & 7) * 8;
            const float* wp = W + (size_t)(k0 + kw) * Kout + col0 + n;
#pragma unroll
            for (int j = 0; j < 8; j++) {
                int c = col0 + n + j;
                Ws[kw][n + j] = (c < Kout) ? wp[j] : 0.f;
            }
        }
        __syncthreads();
#pragma unroll
        for (int k = 0; k < TK; k++) {
            float4 xv4 = *(const float4*)&Xs[k][tr * 4];
            float4 wv4 = *(const float4*)&Ws[k][tc * 4];
            acc[0][0] += xv4.x * wv4.x; acc[0][1] += xv4.x * wv4.y;
            acc[0][2] += xv4.x * wv4.z; acc[0][3] += xv4.x * wv4.w;
            acc[1][0] += xv4.y * wv4.x; acc[1][1] += xv4.y * wv4.y;
            acc[1][2] += xv4.y * wv4.z; acc[1][3] += xv4.y * wv4.w;
            acc[2][0] += xv4.z * wv4.x; acc[2][1] += xv4.z * wv4.y;
            acc[2][2] += xv4.z * wv4.z; acc[2][3] += xv4.z * wv4.w;
            acc[3][0] += xv4.w * wv4.x; acc[3][1] += xv4.w * wv4.y;
            acc[3][2] += xv4.w * wv4.z; acc[3][3] += xv4.w * wv4.w;
        }
        __syncthreads();
    }
#pragma unroll
    for (int i = 0; i < 4; i++) {
        int grow = row0 + tr * 4 + i;
        if (grow >= Nrows) continue;
#pragma unroll
        for (int j = 0; j < 4; j++) {
            int c = col0 + tc * 4 + j;
            if (c < Kout) C[(size_t)grow * Kout + c] = acc[i][j];
        }
    }
}

// ======= fused gather + bias + LN + ReLU (K=128), one wave per node =======
__global__ __launch_bounds__(256) void k_gather_ln(const float* __restrict__ h,
                                                   const int* __restrict__ rend,
                                                   const int* __restrict__ col,
                                                   const float* __restrict__ dinv,
                                                   const float* __restrict__ bias,
                                                   const float* __restrict__ gamma,
                                                   const float* __restrict__ beta,
                                                   float* __restrict__ out) {
    int wave = threadIdx.x >> 6;
    int lane = threadIdx.x & 63;
    int i = blockIdx.x * 4 + wave;
    if (i >= NN) return;
    int start = (i == 0) ? 0 : rend[i - 1];
    int end   = rend[i];
    float di = dinv[i];

    float2 v = *(const float2*)(h + (size_t)i * 128 + lane * 2);
    float a0x = di * di * v.x, a0y = di * di * v.y;   // self-loop
    float a1x = 0.f, a1y = 0.f;

    int j = start;
    for (; j + 2 <= end; j += 2) {
        int s0 = col[j], s1 = col[j + 1];
        float w0 = dinv[s0] * di, w1 = dinv[s1] * di;
        float2 v0 = *(const float2*)(h + (size_t)s0 * 128 + lane * 2);
        float2 v1 = *(const float2*)(h + (size_t)s1 * 128 + lane * 2);
        a0x += w0 * v0.x; a0y += w0 * v0.y;
        a1x += w1 * v1.x; a1y += w1 * v1.y;
    }
    if (j < end) {
        int s0 = col[j];
        float w0 = dinv[s0] * di;
        float2 v0 = *(const float2*)(h + (size_t)s0 * 128 + lane * 2);
        a0x += w0 * v0.x; a0y += w0 * v0.y;
    }
    float2 bb = *(const float2*)(bias + lane * 2);
    float x0 = a0x + a1x + bb.x;
    float x1 = a0y + a1y + bb.y;

    float ssum = x0 + x1;
#pragma unroll
    for (int m = 1; m < 64; m <<= 1) ssum += __shfl_xor(ssum, m);
    float mu = ssum * (1.f / 128.f);
    float d0 = x0 - mu, d1 = x1 - mu;
    float vs = d0 * d0 + d1 * d1;
#pragma unroll
    for (int m = 1; m < 64; m <<= 1) vs += __shfl_xor(vs, m);
    float inv = rsqrtf(vs * (1.f / 128.f) + LN_EPS);
    float2 gg = *(const float2*)(gamma + lane * 2);
    float2 ee = *(const float2*)(beta + lane * 2);
    float o0 = fmaxf(d0 * inv * gg.x + ee.x, 0.f);
    float o1 = fmaxf(d1 * inv * gg.y + ee.y, 0.f);
    *(float2*)(out + (size_t)i * 128 + lane * 2) = make_float2(o0, o1);
}

// ======= fused gather + bias + log_softmax (K=40), one wave per node =======
__global__ __launch_bounds__(256) void k_gather_lsm(const float* __restrict__ h,
                                                    const int* __restrict__ rend,
                                                    const int* __restrict__ col,
                                                    const float* __restrict__ dinv,
                                                    const float* __restrict__ b3,
                                                    float* __restrict__ out) {
    int wave = threadIdx.x >> 6;
    int lane = threadIdx.x & 63;
    int i = blockIdx.x * 4 + wave;
    if (i >= NN) return;
    int start = (i == 0) ? 0 : rend[i - 1];
    int end   = rend[i];
    float di = dinv[i];
    bool act = lane < KCLS;
    int fl = act ? lane : 0;

    float acc = act ? di * di * h[(size_t)i * KCLS + fl] : 0.f;
    for (int j = start; j < end; j++) {
        int s = col[j];
        float w = dinv[s] * di;
        float hv = h[(size_t)s * KCLS + fl];
        if (act) acc += w * hv;
    }
    float v = act ? acc + b3[fl] : -INFINITY;
    float m = v;
#pragma unroll
    for (int msk = 1; msk < 64; msk <<= 1) m = fmaxf(m, __shfl_xor(m, msk));
    float ex = act ? expf(v - m) : 0.f;
    float s = ex;
#pragma unroll
    for (int msk = 1; msk < 64; msk <<= 1) s += __shfl_xor(s, msk);
    if (act) out[(size_t)i * KCLS + lane] = v - m - logf(s);
}

extern "C" void kernel_launch(void* const* d_in, const int* in_sizes, int n_in,
                              void* d_out, int out_size, void* d_ws, size_t ws_size,
                              hipStream_t stream) {
    const float* x   = (const float*)d_in[0];
    const int*   ei  = (const int*)d_in[1];
    const float* W1  = (const float*)d_in[2];
    const float* b1  = (const float*)d_in[3];
    const float* g1  = (const float*)d_in[4];
    const float* be1 = (const float*)d_in[5];
    const float* W2  = (const float*)d_in[6];
    const float* b2  = (const float*)d_in[7];
    const float* g2  = (const float*)d_in[8];
    const float* be2 = (const float*)d_in[9];
    const float* W3  = (const float*)d_in[10];
    const float* b3  = (const float*)d_in[11];
    const int E = in_sizes[1] / 2;
    const int* srcI = ei;
    const int* dstI = ei + E;

    // workspace layout (4-byte elements)
    // [cnt NN][dinv NN][rowptr NN][col E][bufA NN*128][bufB NN*128]
    int*   cnt    = (int*)d_ws;
    float* dinv   = (float*)d_ws + NN;
    int*   rowptr = (int*)d_ws + 2 * NN;
    int*   col    = (int*)d_ws + 3 * NN;
    float* bufA   = (float*)d_ws + 3 * NN + E;          // 16B-aligned (7.6 MB offset)
    float* bufB   = bufA + (size_t)NN * 128;
    float* out    = (float*)d_out;

    dim3 blk(256);

    // ---- CSR build + norm ----
    k_zero_int<<<(NN + 255) / 256, blk, 0, stream>>>(cnt, NN);
    k_count<<<(E + 255) / 256, blk, 0, stream>>>(dstI, cnt, E);
    k_dinv<<<(NN + 255) / 256, blk, 0, stream>>>(cnt, dinv);
    k_scan<<<1, 1024, 0, stream>>>(cnt, rowptr);
    k_fill<<<(E + 255) / 256, blk, 0, stream>>>(srcI, dstI, rowptr, col, E);

    const int gx = (NN + TM - 1) / TM;

    // ---- layer 1 ----
    {
        dim3 grid(gx, (KHID + TN - 1) / TN);
        k_gemm<<<grid, blk, 0, stream>>>(x, W1, bufA, NN, KHID, KHID);
    }
    k_gather_ln<<<(NN + 3) / 4, blk, 0, stream>>>(bufA, rowptr, col, dinv, b1, g1, be1, bufB);

    // ---- layer 2 ----
    {
        dim3 grid(gx, (KHID + TN - 1) / TN);
        k_gemm<<<grid, blk, 0, stream>>>(bufB, W2, bufA, NN, KHID, KHID);
    }
    k_gather_ln<<<(NN + 3) / 4, blk, 0, stream>>>(bufA, rowptr, col, dinv, b2, g2, be2, bufB);

    // ---- layer 3 ----
    float* h3 = bufA;   // NN*40
    {
        dim3 grid(gx, (KCLS + TN - 1) / TN);
        k_gemm<<<grid, blk, 0, stream>>>(bufB, W3, h3, NN, KHID, KCLS);
    }
    k_gather_lsm<<<(NN + 3) / 4, blk, 0, stream>>>(h3, rowptr, col, dinv, b3, out);
}

// Round 3
// 920.237 us; speedup vs baseline: 7.2992x; 1.1344x over previous
//
#include <hip/hip_runtime.h>
#include <math.h>

#define NN 100000
#define KHID 128
#define KCLS 40
#define LN_EPS 1e-5f

// ======================= CSR build =======================
__global__ __launch_bounds__(256) void k_count(const int* __restrict__ dst,
                                               int* __restrict__ cnt, int E) {
    int e = blockIdx.x * 256 + threadIdx.x;
    if (e < E) atomicAdd(&cnt[dst[e]], 1);
}

__global__ __launch_bounds__(256) void k_dinv(const int* __restrict__ cnt,
                                              float* __restrict__ dinv) {
    int i = blockIdx.x * 256 + threadIdx.x;
    if (i < NN) dinv[i] = rsqrtf((float)(1 + cnt[i]));   // +1 self-loop
}

// single-workgroup exclusive scan of cnt[NN] -> rowptr[NN]
__global__ __launch_bounds__(1024) void k_scan(const int* __restrict__ cnt,
                                               int* __restrict__ rowptr) {
    __shared__ int part[1024];
    const int chunk = (NN + 1023) / 1024;
    int t = threadIdx.x;
    int lo = t * chunk, hi = min(lo + chunk, NN);
    int s = 0;
    for (int i = lo; i < hi; i++) s += cnt[i];
    part[t] = s;
    __syncthreads();
    for (int off = 1; off < 1024; off <<= 1) {
        int u = (t >= off) ? part[t - off] : 0;
        __syncthreads();
        part[t] += u;
        __syncthreads();
    }
    int run = (t == 0) ? 0 : part[t - 1];
    for (int i = lo; i < hi; i++) {
        rowptr[i] = run;
        run += cnt[i];
    }
}

// fill: rowptr becomes "end" pointers; start_i = rowptr[i-1] afterwards
__global__ __launch_bounds__(256) void k_fill(const int* __restrict__ src,
                                              const int* __restrict__ dst,
                                              int* __restrict__ rowptr,
                                              int* __restrict__ col, int E) {
    int e = blockIdx.x * 256 + threadIdx.x;
    if (e < E) {
        int pos = atomicAdd(&rowptr[dst[e]], 1);
        col[pos] = src[e];
    }
}

// ======================= GEMM: 128x128 tile, 8x8 acc/thread =======================
#define GTM 128
#define GTN 128
#define GTK 16

__global__ __launch_bounds__(256) void k_gemm(const float* __restrict__ X,
                                              const float* __restrict__ W,
                                              float* __restrict__ C,
                                              int Nrows, int Kin, int Kout) {
    __shared__ float Xs[GTK][GTM + 4];   // [k][m]
    __shared__ float Ws[GTK][GTN + 4];   // [k][n]; +4 breaks 4-way staging conflicts

    int tid  = threadIdx.x;
    int row0 = blockIdx.x * GTM;
    int col0 = blockIdx.y * GTN;
    int tr = tid >> 4;        // rows tr*4 .. +3 and 64+tr*4 .. +3
    int tc = tid & 15;        // cols tc*4 .. +3 and 64+tc*4 .. +3

    float acc[2][2][4][4];
#pragma unroll
    for (int a = 0; a < 2; a++)
#pragma unroll
        for (int b = 0; b < 2; b++)
#pragma unroll
            for (int i = 0; i < 4; i++)
#pragma unroll
                for (int j = 0; j < 4; j++) acc[a][b][i][j] = 0.f;

    for (int k0 = 0; k0 < Kin; k0 += GTK) {
        // stage X: thread -> row tid>>1 (0..127), k-half (tid&1)*8
        {
            int r  = tid >> 1;
            int kh = (tid & 1) * 8;
            int grow = row0 + r;
            float xv[8];
            if (grow < Nrows) {
                const float* xp = X + (size_t)grow * Kin + k0 + kh;
                float4 a = *(const float4*)xp;
                float4 b = *(const float4*)(xp + 4);
                xv[0]=a.x; xv[1]=a.y; xv[2]=a.z; xv[3]=a.w;
                xv[4]=b.x; xv[5]=b.y; xv[6]=b.z; xv[7]=b.w;
            } else {
#pragma unroll
                for (int i = 0; i < 8; i++) xv[i] = 0.f;
            }
#pragma unroll
            for (int i = 0; i < 8; i++) Xs[kh + i][r] = xv[i];
        }
        // stage W: thread -> k tid>>4 (0..15), n (tid&15)*8
        {
            int kw = tid >> 4;
            int n  = (tid & 15) * 8;
            const float* wp = W + (size_t)(k0 + kw) * Kout + col0 + n;
            if (col0 + n + 7 < Kout) {
                float4 a = *(const float4*)wp;
                float4 b = *(const float4*)(wp + 4);
                *(float4*)&Ws[kw][n]     = a;
                *(float4*)&Ws[kw][n + 4] = b;
            } else {
#pragma unroll
                for (int j = 0; j < 8; j++) {
                    int c = col0 + n + j;
                    Ws[kw][n + j] = (c < Kout) ? wp[j] : 0.f;
                }
            }
        }
        __syncthreads();
#pragma unroll
        for (int k = 0; k < GTK; k++) {
            float4 a0 = *(const float4*)&Xs[k][tr * 4];
            float4 a1 = *(const float4*)&Xs[k][64 + tr * 4];
            float4 b0 = *(const float4*)&Ws[k][tc * 4];
            float4 b1 = *(const float4*)&Ws[k][64 + tc * 4];
            float ar[2][4] = {{a0.x,a0.y,a0.z,a0.w},{a1.x,a1.y,a1.z,a1.w}};
            float br[2][4] = {{b0.x,b0.y,b0.z,b0.w},{b1.x,b1.y,b1.z,b1.w}};
#pragma unroll
            for (int a = 0; a < 2; a++)
#pragma unroll
                for (int b = 0; b < 2; b++)
#pragma unroll
                    for (int i = 0; i < 4; i++)
#pragma unroll
                        for (int j = 0; j < 4; j++)
                            acc[a][b][i][j] += ar[a][i] * br[b][j];
        }
        __syncthreads();
    }
#pragma unroll
    for (int a = 0; a < 2; a++)
#pragma unroll
        for (int i = 0; i < 4; i++) {
            int grow = row0 + a * 64 + tr * 4 + i;
            if (grow >= Nrows) continue;
#pragma unroll
            for (int b = 0; b < 2; b++) {
                int gcol = col0 + b * 64 + tc * 4;
                if (gcol + 3 < Kout) {
                    float4 v = make_float4(acc[a][b][i][0], acc[a][b][i][1],
                                           acc[a][b][i][2], acc[a][b][i][3]);
                    *(float4*)(C + (size_t)grow * Kout + gcol) = v;
                } else {
#pragma unroll
                    for (int j = 0; j < 4; j++)
                        if (gcol + j < Kout) C[(size_t)grow * Kout + gcol + j] = acc[a][b][i][j];
                }
            }
        }
}

// ======= fused gather + bias + LN + ReLU (K=128), one wave per node =======
// lanes 0-31: even edges, lanes 32-63: odd edges; float4/lane; batched col/weight prefetch
__global__ __launch_bounds__(256) void k_gather_ln(const float* __restrict__ h,
                                                   const int* __restrict__ rend,
                                                   const int* __restrict__ col,
                                                   const float* __restrict__ dinv,
                                                   const float* __restrict__ bias,
                                                   const float* __restrict__ gamma,
                                                   const float* __restrict__ beta,
                                                   float* __restrict__ out) {
    int wave = threadIdx.x >> 6;
    int lane = threadIdx.x & 63;
    int i = blockIdx.x * 4 + wave;
    if (i >= NN) return;
    int start = (i == 0) ? 0 : rend[i - 1];
    int end   = rend[i];
    float di = dinv[i];
    int half = lane >> 5;
    int fl   = (lane & 31) * 4;

    float ax = 0.f, ay = 0.f, az = 0.f, aw = 0.f;
    if (half == 0) {   // self-loop
        float4 v = *(const float4*)(h + (size_t)i * 128 + fl);
        float w = di * di;
        ax = w * v.x; ay = w * v.y; az = w * v.z; aw = w * v.w;
    }

    for (int b = start; b < end; b += 64) {
        int n = end - b; if (n > 64) n = 64;
        int c = 0; float w = 0.f;
        if (lane < n) { c = col[b + lane]; w = dinv[c] * di; }
        int tmax = (n + 1) >> 1;
        int t = 0;
        for (; t + 4 <= tmax; t += 4) {
            int e0 = 2 * t + half;
            int c0 = __shfl(c, e0),     c1 = __shfl(c, e0 + 2);
            int c2 = __shfl(c, e0 + 4), c3 = __shfl(c, e0 + 6);
            float w0 = __shfl(w, e0),     w1 = __shfl(w, e0 + 2);
            float w2 = __shfl(w, e0 + 4), w3 = __shfl(w, e0 + 6);
            float4 v0 = *(const float4*)(h + (size_t)c0 * 128 + fl);
            float4 v1 = *(const float4*)(h + (size_t)c1 * 128 + fl);
            float4 v2 = *(const float4*)(h + (size_t)c2 * 128 + fl);
            float4 v3 = *(const float4*)(h + (size_t)c3 * 128 + fl);
            ax += w0 * v0.x; ay += w0 * v0.y; az += w0 * v0.z; aw += w0 * v0.w;
            ax += w1 * v1.x; ay += w1 * v1.y; az += w1 * v1.z; aw += w1 * v1.w;
            ax += w2 * v2.x; ay += w2 * v2.y; az += w2 * v2.z; aw += w2 * v2.w;
            ax += w3 * v3.x; ay += w3 * v3.y; az += w3 * v3.z; aw += w3 * v3.w;
        }
        for (; t < tmax; t++) {
            int e0 = 2 * t + half;
            int c0 = __shfl(c, e0);
            float w0 = __shfl(w, e0);
            float4 v0 = *(const float4*)(h + (size_t)c0 * 128 + fl);
            ax += w0 * v0.x; ay += w0 * v0.y; az += w0 * v0.z; aw += w0 * v0.w;
        }
    }
    // merge halves (both halves then hold the full sum for features fl..fl+3)
    ax += __shfl_xor(ax, 32); ay += __shfl_xor(ay, 32);
    az += __shfl_xor(az, 32); aw += __shfl_xor(aw, 32);

    float4 bb = *(const float4*)(bias + fl);
    float x0 = ax + bb.x, x1 = ay + bb.y, x2 = az + bb.z, x3 = aw + bb.w;

    float s = x0 + x1 + x2 + x3;
#pragma unroll
    for (int m = 1; m < 64; m <<= 1) s += __shfl_xor(s, m);   // = 2 * sum(features)
    float mu = s * (1.f / 256.f);
    float d0 = x0 - mu, d1 = x1 - mu, d2 = x2 - mu, d3 = x3 - mu;
    float vs = d0 * d0 + d1 * d1 + d2 * d2 + d3 * d3;
#pragma unroll
    for (int m = 1; m < 64; m <<= 1) vs += __shfl_xor(vs, m);
    float inv = rsqrtf(vs * (1.f / 256.f) + LN_EPS);
    if (half == 0) {
        float4 gg = *(const float4*)(gamma + fl);
        float4 ee = *(const float4*)(beta + fl);
        float4 o;
        o.x = fmaxf(d0 * inv * gg.x + ee.x, 0.f);
        o.y = fmaxf(d1 * inv * gg.y + ee.y, 0.f);
        o.z = fmaxf(d2 * inv * gg.z + ee.z, 0.f);
        o.w = fmaxf(d3 * inv * gg.w + ee.w, 0.f);
        *(float4*)(out + (size_t)i * 128 + fl) = o;
    }
}

// ======= fused gather + bias + log_softmax (K=40), one wave per node =======
__global__ __launch_bounds__(256) void k_gather_lsm(const float* __restrict__ h,
                                                    const int* __restrict__ rend,
                                                    const int* __restrict__ col,
                                                    const float* __restrict__ dinv,
                                                    const float* __restrict__ b3,
                                                    float* __restrict__ out) {
    int wave = threadIdx.x >> 6;
    int lane = threadIdx.x & 63;
    int i = blockIdx.x * 4 + wave;
    if (i >= NN) return;
    int start = (i == 0) ? 0 : rend[i - 1];
    int end   = rend[i];
    float di = dinv[i];
    bool act = lane < KCLS;
    int  fl  = act ? lane : 0;

    float acc = act ? di * di * h[(size_t)i * KCLS + fl] : 0.f;

    for (int b = start; b < end; b += 64) {
        int n = end - b; if (n > 64) n = 64;
        int c = 0; float w = 0.f;
        if (lane < n) { c = col[b + lane]; w = dinv[c] * di; }
        int t = 0;
        for (; t + 4 <= n; t += 4) {
            int c0 = __shfl(c, t),     c1 = __shfl(c, t + 1);
            int c2 = __shfl(c, t + 2), c3 = __shfl(c, t + 3);
            float w0 = __shfl(w, t),     w1 = __shfl(w, t + 1);
            float w2 = __shfl(w, t + 2), w3 = __shfl(w, t + 3);
            float v0 = h[(size_t)c0 * KCLS + fl];
            float v1 = h[(size_t)c1 * KCLS + fl];
            float v2 = h[(size_t)c2 * KCLS + fl];
            float v3 = h[(size_t)c3 * KCLS + fl];
            acc += w0 * v0 + w1 * v1 + w2 * v2 + w3 * v3;
        }
        for (; t < n; t++) {
            int c0 = __shfl(c, t);
            float w0 = __shfl(w, t);
            acc += w0 * h[(size_t)c0 * KCLS + fl];
        }
    }
    float v = act ? acc + b3[fl] : -INFINITY;
    float m = v;
#pragma unroll
    for (int msk = 1; msk < 64; msk <<= 1) m = fmaxf(m, __shfl_xor(m, msk));
    float ex = act ? expf(v - m) : 0.f;
    float s = ex;
#pragma unroll
    for (int msk = 1; msk < 64; msk <<= 1) s += __shfl_xor(s, msk);
    if (act) out[(size_t)i * KCLS + lane] = v - m - logf(s);
}

extern "C" void kernel_launch(void* const* d_in, const int* in_sizes, int n_in,
                              void* d_out, int out_size, void* d_ws, size_t ws_size,
                              hipStream_t stream) {
    const float* x   = (const float*)d_in[0];
    const int*   ei  = (const int*)d_in[1];
    const float* W1  = (const float*)d_in[2];
    const float* b1  = (const float*)d_in[3];
    const float* g1  = (const float*)d_in[4];
    const float* be1 = (const float*)d_in[5];
    const float* W2  = (const float*)d_in[6];
    const float* b2  = (const float*)d_in[7];
    const float* g2  = (const float*)d_in[8];
    const float* be2 = (const float*)d_in[9];
    const float* W3  = (const float*)d_in[10];
    const float* b3  = (const float*)d_in[11];
    const int E = in_sizes[1] / 2;
    const int* srcI = ei;
    const int* dstI = ei + E;

    int*   cnt    = (int*)d_ws;
    float* dinv   = (float*)d_ws + NN;
    int*   rowptr = (int*)d_ws + 2 * NN;
    int*   col    = (int*)d_ws + 3 * NN;
    float* bufA   = (float*)d_ws + 3 * NN + E;   // 16B-aligned
    float* bufB   = bufA + (size_t)NN * 128;
    float* out    = (float*)d_out;

    dim3 blk(256);

    // ---- CSR build + norm ----
    hipMemsetAsync(cnt, 0, NN * sizeof(int), stream);
    k_count<<<(E + 255) / 256, blk, 0, stream>>>(dstI, cnt, E);
    k_dinv<<<(NN + 255) / 256, blk, 0, stream>>>(cnt, dinv);
    k_scan<<<1, 1024, 0, stream>>>(cnt, rowptr);
    k_fill<<<(E + 255) / 256, blk, 0, stream>>>(srcI, dstI, rowptr, col, E);

    const int gx = (NN + GTM - 1) / GTM;

    // ---- layer 1 ----
    {
        dim3 grid(gx, (KHID + GTN - 1) / GTN);
        k_gemm<<<grid, blk, 0, stream>>>(x, W1, bufA, NN, KHID, KHID);
    }
    k_gather_ln<<<(NN + 3) / 4, blk, 0, stream>>>(bufA, rowptr, col, dinv, b1, g1, be1, bufB);

    // ---- layer 2 ----
    {
        dim3 grid(gx, (KHID + GTN - 1) / GTN);
        k_gemm<<<grid, blk, 0, stream>>>(bufB, W2, bufA, NN, KHID, KHID);
    }
    k_gather_ln<<<(NN + 3) / 4, blk, 0, stream>>>(bufA, rowptr, col, dinv, b2, g2, be2, bufB);

    // ---- layer 3 ----
    float* h3 = bufA;   // NN*40
    {
        dim3 grid(gx, (KCLS + GTN - 1) / GTN);
        k_gemm<<<grid, blk, 0, stream>>>(bufB, W3, h3, NN, KHID, KCLS);
    }
    k_gather_lsm<<<(NN + 3) / 4, blk, 0, stream>>>(h3, rowptr, col, dinv, b3, out);
}

// Round 4
// 762.587 us; speedup vs baseline: 8.8081x; 1.2067x over previous
//
#include <hip/hip_runtime.h>
#include <math.h>

#define NN 100000
#define KHID 128
#define KCLS 40
#define LN_EPS 1e-5f
#define SCAN_B 1024
#define SCAN_NB ((NN + SCAN_B - 1) / SCAN_B)   // 98

// ======================= CSR build =======================
__global__ __launch_bounds__(256) void k_count(const int* __restrict__ dst,
                                               int* __restrict__ cnt, int E) {
    int e = blockIdx.x * 256 + threadIdx.x;
    if (e < E) atomicAdd(&cnt[dst[e]], 1);
}

__global__ __launch_bounds__(256) void k_dinv(const int* __restrict__ cnt,
                                              float* __restrict__ dinv) {
    int i = blockIdx.x * 256 + threadIdx.x;
    if (i < NN) dinv[i] = rsqrtf((float)(1 + cnt[i]));   // +1 self-loop
}

// ---- parallel scan, 3 kernels ----
__global__ __launch_bounds__(SCAN_B) void k_blocksum(const int* __restrict__ cnt,
                                                     int* __restrict__ bsum) {
    __shared__ int wsum[16];
    int t = threadIdx.x, lane = t & 63, wv = t >> 6;
    int i = blockIdx.x * SCAN_B + t;
    int v = (i < NN) ? cnt[i] : 0;
#pragma unroll
    for (int m = 1; m < 64; m <<= 1) v += __shfl_xor(v, m);
    if (lane == 0) wsum[wv] = v;
    __syncthreads();
    if (t == 0) {
        int s = 0;
#pragma unroll
        for (int w = 0; w < 16; w++) s += wsum[w];
        bsum[blockIdx.x] = s;
    }
}

// single block, 128 threads: exclusive scan of bsum[SCAN_NB] in place
__global__ __launch_bounds__(128) void k_scan_bsums(int* __restrict__ bsum) {
    __shared__ int ws[2];
    int t = threadIdx.x, lane = t & 63, wv = t >> 6;
    int v = (t < SCAN_NB) ? bsum[t] : 0;
    int s = v;
#pragma unroll
    for (int off = 1; off < 64; off <<= 1) {
        int u = __shfl_up(s, off);
        if (lane >= off) s += u;
    }
    if (lane == 63) ws[wv] = s;
    __syncthreads();
    int add = (wv == 1) ? ws[0] : 0;
    if (t < SCAN_NB) bsum[t] = s + add - v;   // exclusive
}

// rowptr[i] = bsum_ex[b] + exclusive in-block prefix
__global__ __launch_bounds__(SCAN_B) void k_scan_final(const int* __restrict__ cnt,
                                                       const int* __restrict__ bsum,
                                                       int* __restrict__ rowptr) {
    __shared__ int wsum[16];
    int t = threadIdx.x, lane = t & 63, wv = t >> 6;
    int i = blockIdx.x * SCAN_B + t;
    int v = (i < NN) ? cnt[i] : 0;
    int s = v;
#pragma unroll
    for (int off = 1; off < 64; off <<= 1) {
        int u = __shfl_up(s, off);
        if (lane >= off) s += u;
    }
    if (lane == 63) wsum[wv] = s;
    __syncthreads();
    int woff = 0;
    for (int w = 0; w < wv; w++) woff += wsum[w];
    if (i < NN) rowptr[i] = bsum[blockIdx.x] + woff + s - v;
}

// fill: rowptr becomes "end" pointers; start_i = rowptr[i-1] afterwards
__global__ __launch_bounds__(256) void k_fill(const int* __restrict__ src,
                                              const int* __restrict__ dst,
                                              int* __restrict__ rowptr,
                                              int* __restrict__ col, int E) {
    int e = blockIdx.x * 256 + threadIdx.x;
    if (e < E) {
        int pos = atomicAdd(&rowptr[dst[e]], 1);
        col[pos] = src[e];
    }
}

// ======================= GEMM: 128x128 tile, 8x8 acc/thread =======================
#define GTM 128
#define GTN 128
#define GTK 16

__global__ __launch_bounds__(256) void k_gemm(const float* __restrict__ X,
                                              const float* __restrict__ W,
                                              float* __restrict__ C,
                                              int Nrows, int Kin, int Kout) {
    __shared__ float Xs[GTK][GTM + 4];
    __shared__ float Ws[GTK][GTN + 4];

    int tid  = threadIdx.x;
    int row0 = blockIdx.x * GTM;
    int col0 = blockIdx.y * GTN;
    int tr = tid >> 4;
    int tc = tid & 15;

    float acc[2][2][4][4];
#pragma unroll
    for (int a = 0; a < 2; a++)
#pragma unroll
        for (int b = 0; b < 2; b++)
#pragma unroll
            for (int i = 0; i < 4; i++)
#pragma unroll
                for (int j = 0; j < 4; j++) acc[a][b][i][j] = 0.f;

    for (int k0 = 0; k0 < Kin; k0 += GTK) {
        {
            int r  = tid >> 1;
            int kh = (tid & 1) * 8;
            int grow = row0 + r;
            float xv[8];
            if (grow < Nrows) {
                const float* xp = X + (size_t)grow * Kin + k0 + kh;
                float4 a = *(const float4*)xp;
                float4 b = *(const float4*)(xp + 4);
                xv[0]=a.x; xv[1]=a.y; xv[2]=a.z; xv[3]=a.w;
                xv[4]=b.x; xv[5]=b.y; xv[6]=b.z; xv[7]=b.w;
            } else {
#pragma unroll
                for (int i = 0; i < 8; i++) xv[i] = 0.f;
            }
#pragma unroll
            for (int i = 0; i < 8; i++) Xs[kh + i][r] = xv[i];
        }
        {
            int kw = tid >> 4;
            int n  = (tid & 15) * 8;
            const float* wp = W + (size_t)(k0 + kw) * Kout + col0 + n;
            if (col0 + n + 7 < Kout) {
                *(float4*)&Ws[kw][n]     = *(const float4*)wp;
                *(float4*)&Ws[kw][n + 4] = *(const float4*)(wp + 4);
            } else {
#pragma unroll
                for (int j = 0; j < 8; j++) {
                    int c = col0 + n + j;
                    Ws[kw][n + j] = (c < Kout) ? wp[j] : 0.f;
                }
            }
        }
        __syncthreads();
#pragma unroll
        for (int k = 0; k < GTK; k++) {
            float4 a0 = *(const float4*)&Xs[k][tr * 4];
            float4 a1 = *(const float4*)&Xs[k][64 + tr * 4];
            float4 b0 = *(const float4*)&Ws[k][tc * 4];
            float4 b1 = *(const float4*)&Ws[k][64 + tc * 4];
            float ar[2][4] = {{a0.x,a0.y,a0.z,a0.w},{a1.x,a1.y,a1.z,a1.w}};
            float br[2][4] = {{b0.x,b0.y,b0.z,b0.w},{b1.x,b1.y,b1.z,b1.w}};
#pragma unroll
            for (int a = 0; a < 2; a++)
#pragma unroll
                for (int b = 0; b < 2; b++)
#pragma unroll
                    for (int i = 0; i < 4; i++)
#pragma unroll
                        for (int j = 0; j < 4; j++)
                            acc[a][b][i][j] += ar[a][i] * br[b][j];
        }
        __syncthreads();
    }
#pragma unroll
    for (int a = 0; a < 2; a++)
#pragma unroll
        for (int i = 0; i < 4; i++) {
            int grow = row0 + a * 64 + tr * 4 + i;
            if (grow >= Nrows) continue;
#pragma unroll
            for (int b = 0; b < 2; b++) {
                int gcol = col0 + b * 64 + tc * 4;
                if (gcol + 3 < Kout) {
                    float4 v = make_float4(acc[a][b][i][0], acc[a][b][i][1],
                                           acc[a][b][i][2], acc[a][b][i][3]);
                    *(float4*)(C + (size_t)grow * Kout + gcol) = v;
                } else {
#pragma unroll
                    for (int j = 0; j < 4; j++)
                        if (gcol + j < Kout) C[(size_t)grow * Kout + gcol + j] = acc[a][b][i][j];
                }
            }
        }
}

// ======= fused gather + bias + LN + ReLU (K=128), one wave per node =======
__global__ __launch_bounds__(256) void k_gather_ln(const float* __restrict__ h,
                                                   const int* __restrict__ rend,
                                                   const int* __restrict__ col,
                                                   const float* __restrict__ dinv,
                                                   const float* __restrict__ bias,
                                                   const float* __restrict__ gamma,
                                                   const float* __restrict__ beta,
                                                   float* __restrict__ out) {
    int wave = threadIdx.x >> 6;
    int lane = threadIdx.x & 63;
    int i = blockIdx.x * 4 + wave;
    if (i >= NN) return;
    int start = (i == 0) ? 0 : rend[i - 1];
    int end   = rend[i];
    float di = dinv[i];
    int half = lane >> 5;
    int fl   = (lane & 31) * 4;

    float ax = 0.f, ay = 0.f, az = 0.f, aw = 0.f;
    if (half == 0) {   // self-loop
        float4 v = *(const float4*)(h + (size_t)i * 128 + fl);
        float w = di * di;
        ax = w * v.x; ay = w * v.y; az = w * v.z; aw = w * v.w;
    }

    for (int b = start; b < end; b += 64) {
        int n = end - b; if (n > 64) n = 64;
        int c = 0; float w = 0.f;
        if (lane < n) { c = col[b + lane]; w = dinv[c] * di; }
        int tmax = (n + 1) >> 1;
        int t = 0;
        for (; t + 4 <= tmax; t += 4) {
            int e0 = 2 * t + half;
            int c0 = __shfl(c, e0),     c1 = __shfl(c, e0 + 2);
            int c2 = __shfl(c, e0 + 4), c3 = __shfl(c, e0 + 6);
            float w0 = __shfl(w, e0),     w1 = __shfl(w, e0 + 2);
            float w2 = __shfl(w, e0 + 4), w3 = __shfl(w, e0 + 6);
            float4 v0 = *(const float4*)(h + (size_t)c0 * 128 + fl);
            float4 v1 = *(const float4*)(h + (size_t)c1 * 128 + fl);
            float4 v2 = *(const float4*)(h + (size_t)c2 * 128 + fl);
            float4 v3 = *(const float4*)(h + (size_t)c3 * 128 + fl);
            ax += w0 * v0.x; ay += w0 * v0.y; az += w0 * v0.z; aw += w0 * v0.w;
            ax += w1 * v1.x; ay += w1 * v1.y; az += w1 * v1.z; aw += w1 * v1.w;
            ax += w2 * v2.x; ay += w2 * v2.y; az += w2 * v2.z; aw += w2 * v2.w;
            ax += w3 * v3.x; ay += w3 * v3.y; az += w3 * v3.z; aw += w3 * v3.w;
        }
        for (; t < tmax; t++) {
            int e0 = 2 * t + half;
            int c0 = __shfl(c, e0);
            float w0 = __shfl(w, e0);
            float4 v0 = *(const float4*)(h + (size_t)c0 * 128 + fl);
            ax += w0 * v0.x; ay += w0 * v0.y; az += w0 * v0.z; aw += w0 * v0.w;
        }
    }
    ax += __shfl_xor(ax, 32); ay += __shfl_xor(ay, 32);
    az += __shfl_xor(az, 32); aw += __shfl_xor(aw, 32);

    float4 bb = *(const float4*)(bias + fl);
    float x0 = ax + bb.x, x1 = ay + bb.y, x2 = az + bb.z, x3 = aw + bb.w;

    float s = x0 + x1 + x2 + x3;
#pragma unroll
    for (int m = 1; m < 64; m <<= 1) s += __shfl_xor(s, m);
    float mu = s * (1.f / 256.f);
    float d0 = x0 - mu, d1 = x1 - mu, d2 = x2 - mu, d3 = x3 - mu;
    float vs = d0 * d0 + d1 * d1 + d2 * d2 + d3 * d3;
#pragma unroll
    for (int m = 1; m < 64; m <<= 1) vs += __shfl_xor(vs, m);
    float inv = rsqrtf(vs * (1.f / 256.f) + LN_EPS);
    if (half == 0) {
        float4 gg = *(const float4*)(gamma + fl);
        float4 ee = *(const float4*)(beta + fl);
        float4 o;
        o.x = fmaxf(d0 * inv * gg.x + ee.x, 0.f);
        o.y = fmaxf(d1 * inv * gg.y + ee.y, 0.f);
        o.z = fmaxf(d2 * inv * gg.z + ee.z, 0.f);
        o.w = fmaxf(d3 * inv * gg.w + ee.w, 0.f);
        *(float4*)(out + (size_t)i * 128 + fl) = o;
    }
}

// ======= fused gather + bias + log_softmax (K=40), one wave per node =======
__global__ __launch_bounds__(256) void k_gather_lsm(const float* __restrict__ h,
                                                    const int* __restrict__ rend,
                                                    const int* __restrict__ col,
                                                    const float* __restrict__ dinv,
                                                    const float* __restrict__ b3,
                                                    float* __restrict__ out) {
    int wave = threadIdx.x >> 6;
    int lane = threadIdx.x & 63;
    int i = blockIdx.x * 4 + wave;
    if (i >= NN) return;
    int start = (i == 0) ? 0 : rend[i - 1];
    int end   = rend[i];
    float di = dinv[i];
    bool act = lane < KCLS;
    int  fl  = act ? lane : 0;

    float acc = act ? di * di * h[(size_t)i * KCLS + fl] : 0.f;

    for (int b = start; b < end; b += 64) {
        int n = end - b; if (n > 64) n = 64;
        int c = 0; float w = 0.f;
        if (lane < n) { c = col[b + lane]; w = dinv[c] * di; }
        int t = 0;
        for (; t + 4 <= n; t += 4) {
            int c0 = __shfl(c, t),     c1 = __shfl(c, t + 1);
            int c2 = __shfl(c, t + 2), c3 = __shfl(c, t + 3);
            float w0 = __shfl(w, t),     w1 = __shfl(w, t + 1);
            float w2 = __shfl(w, t + 2), w3 = __shfl(w, t + 3);
            float v0 = h[(size_t)c0 * KCLS + fl];
            float v1 = h[(size_t)c1 * KCLS + fl];
            float v2 = h[(size_t)c2 * KCLS + fl];
            float v3 = h[(size_t)c3 * KCLS + fl];
            acc += w0 * v0 + w1 * v1 + w2 * v2 + w3 * v3;
        }
        for (; t < n; t++) {
            int c0 = __shfl(c, t);
            float w0 = __shfl(w, t);
            acc += w0 * h[(size_t)c0 * KCLS + fl];
        }
    }
    float v = act ? acc + b3[fl] : -INFINITY;
    float m = v;
#pragma unroll
    for (int msk = 1; msk < 64; msk <<= 1) m = fmaxf(m, __shfl_xor(m, msk));
    float ex = act ? expf(v - m) : 0.f;
    float s = ex;
#pragma unroll
    for (int msk = 1; msk < 64; msk <<= 1) s += __shfl_xor(s, msk);
    if (act) out[(size_t)i * KCLS + lane] = v - m - logf(s);
}

extern "C" void kernel_launch(void* const* d_in, const int* in_sizes, int n_in,
                              void* d_out, int out_size, void* d_ws, size_t ws_size,
                              hipStream_t stream) {
    const float* x   = (const float*)d_in[0];
    const int*   ei  = (const int*)d_in[1];
    const float* W1  = (const float*)d_in[2];
    const float* b1  = (const float*)d_in[3];
    const float* g1  = (const float*)d_in[4];
    const float* be1 = (const float*)d_in[5];
    const float* W2  = (const float*)d_in[6];
    const float* b2  = (const float*)d_in[7];
    const float* g2  = (const float*)d_in[8];
    const float* be2 = (const float*)d_in[9];
    const float* W3  = (const float*)d_in[10];
    const float* b3  = (const float*)d_in[11];
    const int E = in_sizes[1] / 2;
    const int* srcI = ei;
    const int* dstI = ei + E;

    int*   cnt    = (int*)d_ws;
    float* dinv   = (float*)d_ws + NN;
    int*   rowptr = (int*)d_ws + 2 * NN;
    int*   bsum   = (int*)d_ws + 3 * NN;               // [SCAN_NB], padded to 512
    int*   col    = (int*)d_ws + 3 * NN + 512;
    float* bufA   = (float*)d_ws + 3 * NN + 512 + E;   // 16B-aligned
    float* bufB   = bufA + (size_t)NN * 128;
    float* out    = (float*)d_out;

    dim3 blk(256);

    // ---- CSR build + norm ----
    hipMemsetAsync(cnt, 0, NN * sizeof(int), stream);
    k_count<<<(E + 255) / 256, blk, 0, stream>>>(dstI, cnt, E);
    k_dinv<<<(NN + 255) / 256, blk, 0, stream>>>(cnt, dinv);
    k_blocksum<<<SCAN_NB, SCAN_B, 0, stream>>>(cnt, bsum);
    k_scan_bsums<<<1, 128, 0, stream>>>(bsum);
    k_scan_final<<<SCAN_NB, SCAN_B, 0, stream>>>(cnt, bsum, rowptr);
    k_fill<<<(E + 255) / 256, blk, 0, stream>>>(srcI, dstI, rowptr, col, E);

    const int gx = (NN + GTM - 1) / GTM;

    // ---- layer 1 ----
    {
        dim3 grid(gx, (KHID + GTN - 1) / GTN);
        k_gemm<<<grid, blk, 0, stream>>>(x, W1, bufA, NN, KHID, KHID);
    }
    k_gather_ln<<<(NN + 3) / 4, blk, 0, stream>>>(bufA, rowptr, col, dinv, b1, g1, be1, bufB);

    // ---- layer 2 ----
    {
        dim3 grid(gx, (KHID + GTN - 1) / GTN);
        k_gemm<<<grid, blk, 0, stream>>>(bufB, W2, bufA, NN, KHID, KHID);
    }
    k_gather_ln<<<(NN + 3) / 4, blk, 0, stream>>>(bufA, rowptr, col, dinv, b2, g2, be2, bufB);

    // ---- layer 3 ----
    float* h3 = bufA;   // NN*40
    {
        dim3 grid(gx, (KCLS + GTN - 1) / GTN);
        k_gemm<<<grid, blk, 0, stream>>>(bufB, W3, h3, NN, KHID, KCLS);
    }
    k_gather_lsm<<<(NN + 3) / 4, blk, 0, stream>>>(h3, rowptr, col, dinv, b3, out);
}

// Round 5
// 697.396 us; speedup vs baseline: 9.6315x; 1.0935x over previous
//
#include <hip/hip_runtime.h>
#include <math.h>

#define NN 100000
#define KHID 128
#define KCLS 40
#define LN_EPS 1e-5f
#define SCAN_B 1024
#define SCAN_NB ((NN + SCAN_B - 1) / SCAN_B)   // 98
#define NBKT ((NN + 255) >> 8)                 // 391 buckets of 256 nodes
#define PCHUNK 4096                            // edges per partition workgroup

// ======================= CSR build =======================
__global__ __launch_bounds__(256) void k_count(const int* __restrict__ dst,
                                               int* __restrict__ cnt, int E) {
    int e = blockIdx.x * 256 + threadIdx.x;
    if (e < E) atomicAdd(&cnt[dst[e]], 1);
}

__global__ __launch_bounds__(256) void k_dinv(const int* __restrict__ cnt,
                                              float* __restrict__ dinv) {
    int i = blockIdx.x * 256 + threadIdx.x;
    if (i < NN) dinv[i] = rsqrtf((float)(1 + cnt[i]));   // +1 self-loop
}

// ---- parallel scan, 3 kernels ----
__global__ __launch_bounds__(SCAN_B) void k_blocksum(const int* __restrict__ cnt,
                                                     int* __restrict__ bsum) {
    __shared__ int wsum[16];
    int t = threadIdx.x, lane = t & 63, wv = t >> 6;
    int i = blockIdx.x * SCAN_B + t;
    int v = (i < NN) ? cnt[i] : 0;
#pragma unroll
    for (int m = 1; m < 64; m <<= 1) v += __shfl_xor(v, m);
    if (lane == 0) wsum[wv] = v;
    __syncthreads();
    if (t == 0) {
        int s = 0;
#pragma unroll
        for (int w = 0; w < 16; w++) s += wsum[w];
        bsum[blockIdx.x] = s;
    }
}

__global__ __launch_bounds__(128) void k_scan_bsums(int* __restrict__ bsum) {
    __shared__ int ws[2];
    int t = threadIdx.x, lane = t & 63, wv = t >> 6;
    int v = (t < SCAN_NB) ? bsum[t] : 0;
    int s = v;
#pragma unroll
    for (int off = 1; off < 64; off <<= 1) {
        int u = __shfl_up(s, off);
        if (lane >= off) s += u;
    }
    if (lane == 63) ws[wv] = s;
    __syncthreads();
    int add = (wv == 1) ? ws[0] : 0;
    if (t < SCAN_NB) bsum[t] = s + add - v;   // exclusive
}

__global__ __launch_bounds__(SCAN_B) void k_scan_final(const int* __restrict__ cnt,
                                                       const int* __restrict__ bsum,
                                                       int* __restrict__ rowptr) {
    __shared__ int wsum[16];
    int t = threadIdx.x, lane = t & 63, wv = t >> 6;
    int i = blockIdx.x * SCAN_B + t;
    int v = (i < NN) ? cnt[i] : 0;
    int s = v;
#pragma unroll
    for (int off = 1; off < 64; off <<= 1) {
        int u = __shfl_up(s, off);
        if (lane >= off) s += u;
    }
    if (lane == 63) wsum[wv] = s;
    __syncthreads();
    int woff = 0;
    for (int w = 0; w < wv; w++) woff += wsum[w];
    if (i < NN) rowptr[i] = bsum[blockIdx.x] + woff + s - v;
}

// btail[b] = exclusive start of bucket b's col region (mutates to end after k_part)
__global__ __launch_bounds__(256) void k_btail(const int* __restrict__ rowptr,
                                               int* __restrict__ btail) {
    int b = blockIdx.x * 256 + threadIdx.x;
    if (b < NBKT) btail[b] = rowptr[b << 8];
}

// pass 1: partition edges into dst-buckets; ebuf[pos] = (dst&255)<<20 | src
__global__ __launch_bounds__(256) void k_part(const int* __restrict__ srcA,
                                              const int* __restrict__ dstA,
                                              int* __restrict__ btail,
                                              int* __restrict__ ebuf, int E) {
    __shared__ int hist[NBKT];
    int tid = threadIdx.x;
    int base = blockIdx.x * PCHUNK;
    int sreg[PCHUNK / 256], dreg[PCHUNK / 256];

    for (int k = tid; k < NBKT; k += 256) hist[k] = 0;
    __syncthreads();
#pragma unroll
    for (int j = 0; j < PCHUNK / 256; j++) {
        int e = base + j * 256 + tid;
        if (e < E) {
            sreg[j] = srcA[e];
            int d = dstA[e];
            dreg[j] = d;
            atomicAdd(&hist[d >> 8], 1);
        } else dreg[j] = -1;
    }
    __syncthreads();
    for (int k = tid; k < NBKT; k += 256)
        hist[k] = atomicAdd(&btail[k], hist[k]);   // hist becomes global cursor base
    __syncthreads();
#pragma unroll
    for (int j = 0; j < PCHUNK / 256; j++) {
        int d = dreg[j];
        if (d >= 0) {
            int pos = atomicAdd(&hist[d >> 8], 1);
            ebuf[pos] = ((d & 255) << 20) | sreg[j];
        }
    }
}

// pass 2: within-bucket scatter (L2-resident region per workgroup)
__global__ __launch_bounds__(256) void k_fill2(const int* __restrict__ ebuf,
                                               const int* __restrict__ btail,
                                               int* __restrict__ rowptr,
                                               int* __restrict__ col) {
    int b = blockIdx.x;
    int bstart = (b == 0) ? 0 : btail[b - 1];
    int bend   = btail[b];
    int nb = b << 8;
    for (int e = bstart + threadIdx.x; e < bend; e += 256) {
        int p = ebuf[e];
        int d = nb + (p >> 20);
        int s = p & 0xFFFFF;
        int pos = atomicAdd(&rowptr[d], 1);
        col[pos] = s;
    }
}

// ======================= GEMM: 128x128 tile, 8x8 acc/thread =======================
#define GTM 128
#define GTN 128
#define GTK 16

__global__ __launch_bounds__(256) void k_gemm(const float* __restrict__ X,
                                              const float* __restrict__ W,
                                              float* __restrict__ C,
                                              int Nrows, int Kin, int Kout) {
    __shared__ float Xs[GTK][GTM + 4];
    __shared__ float Ws[GTK][GTN + 4];

    int tid  = threadIdx.x;
    int row0 = blockIdx.x * GTM;
    int col0 = blockIdx.y * GTN;
    int tr = tid >> 4;
    int tc = tid & 15;

    float acc[2][2][4][4];
#pragma unroll
    for (int a = 0; a < 2; a++)
#pragma unroll
        for (int b = 0; b < 2; b++)
#pragma unroll
            for (int i = 0; i < 4; i++)
#pragma unroll
                for (int j = 0; j < 4; j++) acc[a][b][i][j] = 0.f;

    for (int k0 = 0; k0 < Kin; k0 += GTK) {
        {
            int r  = tid >> 1;
            int kh = (tid & 1) * 8;
            int grow = row0 + r;
            float xv[8];
            if (grow < Nrows) {
                const float* xp = X + (size_t)grow * Kin + k0 + kh;
                float4 a = *(const float4*)xp;
                float4 b = *(const float4*)(xp + 4);
                xv[0]=a.x; xv[1]=a.y; xv[2]=a.z; xv[3]=a.w;
                xv[4]=b.x; xv[5]=b.y; xv[6]=b.z; xv[7]=b.w;
            } else {
#pragma unroll
                for (int i = 0; i < 8; i++) xv[i] = 0.f;
            }
#pragma unroll
            for (int i = 0; i < 8; i++) Xs[kh + i][r] = xv[i];
        }
        {
            int kw = tid >> 4;
            int n  = (tid & 15) * 8;
            const float* wp = W + (size_t)(k0 + kw) * Kout + col0 + n;
            if (col0 + n + 7 < Kout) {
                *(float4*)&Ws[kw][n]     = *(const float4*)wp;
                *(float4*)&Ws[kw][n + 4] = *(const float4*)(wp + 4);
            } else {
#pragma unroll
                for (int j = 0; j < 8; j++) {
                    int c = col0 + n + j;
                    Ws[kw][n + j] = (c < Kout) ? wp[j] : 0.f;
                }
            }
        }
        __syncthreads();
#pragma unroll
        for (int k = 0; k < GTK; k++) {
            float4 a0 = *(const float4*)&Xs[k][tr * 4];
            float4 a1 = *(const float4*)&Xs[k][64 + tr * 4];
            float4 b0 = *(const float4*)&Ws[k][tc * 4];
            float4 b1 = *(const float4*)&Ws[k][64 + tc * 4];
            float ar[2][4] = {{a0.x,a0.y,a0.z,a0.w},{a1.x,a1.y,a1.z,a1.w}};
            float br[2][4] = {{b0.x,b0.y,b0.z,b0.w},{b1.x,b1.y,b1.z,b1.w}};
#pragma unroll
            for (int a = 0; a < 2; a++)
#pragma unroll
                for (int b = 0; b < 2; b++)
#pragma unroll
                    for (int i = 0; i < 4; i++)
#pragma unroll
                        for (int j = 0; j < 4; j++)
                            acc[a][b][i][j] += ar[a][i] * br[b][j];
        }
        __syncthreads();
    }
#pragma unroll
    for (int a = 0; a < 2; a++)
#pragma unroll
        for (int i = 0; i < 4; i++) {
            int grow = row0 + a * 64 + tr * 4 + i;
            if (grow >= Nrows) continue;
#pragma unroll
            for (int b = 0; b < 2; b++) {
                int gcol = col0 + b * 64 + tc * 4;
                if (gcol + 3 < Kout) {
                    float4 v = make_float4(acc[a][b][i][0], acc[a][b][i][1],
                                           acc[a][b][i][2], acc[a][b][i][3]);
                    *(float4*)(C + (size_t)grow * Kout + gcol) = v;
                } else {
#pragma unroll
                    for (int j = 0; j < 4; j++)
                        if (gcol + j < Kout) C[(size_t)grow * Kout + gcol + j] = acc[a][b][i][j];
                }
            }
        }
}

// ======= fused gather + bias + LN + ReLU (K=128), one wave per node =======
__global__ __launch_bounds__(256) void k_gather_ln(const float* __restrict__ h,
                                                   const int* __restrict__ rend,
                                                   const int* __restrict__ col,
                                                   const float* __restrict__ dinv,
                                                   const float* __restrict__ bias,
                                                   const float* __restrict__ gamma,
                                                   const float* __restrict__ beta,
                                                   float* __restrict__ out) {
    int wave = threadIdx.x >> 6;
    int lane = threadIdx.x & 63;
    int i = blockIdx.x * 4 + wave;
    if (i >= NN) return;
    int start = (i == 0) ? 0 : rend[i - 1];
    int end   = rend[i];
    float di = dinv[i];
    int half = lane >> 5;
    int fl   = (lane & 31) * 4;

    float ax = 0.f, ay = 0.f, az = 0.f, aw = 0.f;
    if (half == 0) {   // self-loop
        float4 v = *(const float4*)(h + (size_t)i * 128 + fl);
        float w = di * di;
        ax = w * v.x; ay = w * v.y; az = w * v.z; aw = w * v.w;
    }

    for (int b = start; b < end; b += 64) {
        int n = end - b; if (n > 64) n = 64;
        int c = 0; float w = 0.f;
        if (lane < n) { c = col[b + lane]; w = dinv[c] * di; }
        int tmax = (n + 1) >> 1;
        int t = 0;
        for (; t + 4 <= tmax; t += 4) {
            int e0 = 2 * t + half;
            int c0 = __shfl(c, e0),     c1 = __shfl(c, e0 + 2);
            int c2 = __shfl(c, e0 + 4), c3 = __shfl(c, e0 + 6);
            float w0 = __shfl(w, e0),     w1 = __shfl(w, e0 + 2);
            float w2 = __shfl(w, e0 + 4), w3 = __shfl(w, e0 + 6);
            float4 v0 = *(const float4*)(h + (size_t)c0 * 128 + fl);
            float4 v1 = *(const float4*)(h + (size_t)c1 * 128 + fl);
            float4 v2 = *(const float4*)(h + (size_t)c2 * 128 + fl);
            float4 v3 = *(const float4*)(h + (size_t)c3 * 128 + fl);
            ax += w0 * v0.x; ay += w0 * v0.y; az += w0 * v0.z; aw += w0 * v0.w;
            ax += w1 * v1.x; ay += w1 * v1.y; az += w1 * v1.z; aw += w1 * v1.w;
            ax += w2 * v2.x; ay += w2 * v2.y; az += w2 * v2.z; aw += w2 * v2.w;
            ax += w3 * v3.x; ay += w3 * v3.y; az += w3 * v3.z; aw += w3 * v3.w;
        }
        for (; t < tmax; t++) {
            int e0 = 2 * t + half;
            int c0 = __shfl(c, e0);
            float w0 = __shfl(w, e0);
            float4 v0 = *(const float4*)(h + (size_t)c0 * 128 + fl);
            ax += w0 * v0.x; ay += w0 * v0.y; az += w0 * v0.z; aw += w0 * v0.w;
        }
    }
    ax += __shfl_xor(ax, 32); ay += __shfl_xor(ay, 32);
    az += __shfl_xor(az, 32); aw += __shfl_xor(aw, 32);

    float4 bb = *(const float4*)(bias + fl);
    float x0 = ax + bb.x, x1 = ay + bb.y, x2 = az + bb.z, x3 = aw + bb.w;

    float s = x0 + x1 + x2 + x3;
#pragma unroll
    for (int m = 1; m < 64; m <<= 1) s += __shfl_xor(s, m);
    float mu = s * (1.f / 256.f);
    float d0 = x0 - mu, d1 = x1 - mu, d2 = x2 - mu, d3 = x3 - mu;
    float vs = d0 * d0 + d1 * d1 + d2 * d2 + d3 * d3;
#pragma unroll
    for (int m = 1; m < 64; m <<= 1) vs += __shfl_xor(vs, m);
    float inv = rsqrtf(vs * (1.f / 256.f) + LN_EPS);
    if (half == 0) {
        float4 gg = *(const float4*)(gamma + fl);
        float4 ee = *(const float4*)(beta + fl);
        float4 o;
        o.x = fmaxf(d0 * inv * gg.x + ee.x, 0.f);
        o.y = fmaxf(d1 * inv * gg.y + ee.y, 0.f);
        o.z = fmaxf(d2 * inv * gg.z + ee.z, 0.f);
        o.w = fmaxf(d3 * inv * gg.w + ee.w, 0.f);
        *(float4*)(out + (size_t)i * 128 + fl) = o;
    }
}

// ======= fused gather + bias + log_softmax (K=40), one wave per node =======
__global__ __launch_bounds__(256) void k_gather_lsm(const float* __restrict__ h,
                                                    const int* __restrict__ rend,
                                                    const int* __restrict__ col,
                                                    const float* __restrict__ dinv,
                                                    const float* __restrict__ b3,
                                                    float* __restrict__ out) {
    int wave = threadIdx.x >> 6;
    int lane = threadIdx.x & 63;
    int i = blockIdx.x * 4 + wave;
    if (i >= NN) return;
    int start = (i == 0) ? 0 : rend[i - 1];
    int end   = rend[i];
    float di = dinv[i];
    bool act = lane < KCLS;
    int  fl  = act ? lane : 0;

    float acc = act ? di * di * h[(size_t)i * KCLS + fl] : 0.f;

    for (int b = start; b < end; b += 64) {
        int n = end - b; if (n > 64) n = 64;
        int c = 0; float w = 0.f;
        if (lane < n) { c = col[b + lane]; w = dinv[c] * di; }
        int t = 0;
        for (; t + 4 <= n; t += 4) {
            int c0 = __shfl(c, t),     c1 = __shfl(c, t + 1);
            int c2 = __shfl(c, t + 2), c3 = __shfl(c, t + 3);
            float w0 = __shfl(w, t),     w1 = __shfl(w, t + 1);
            float w2 = __shfl(w, t + 2), w3 = __shfl(w, t + 3);
            float v0 = h[(size_t)c0 * KCLS + fl];
            float v1 = h[(size_t)c1 * KCLS + fl];
            float v2 = h[(size_t)c2 * KCLS + fl];
            float v3 = h[(size_t)c3 * KCLS + fl];
            acc += w0 * v0 + w1 * v1 + w2 * v2 + w3 * v3;
        }
        for (; t < n; t++) {
            int c0 = __shfl(c, t);
            float w0 = __shfl(w, t);
            acc += w0 * h[(size_t)c0 * KCLS + fl];
        }
    }
    float v = act ? acc + b3[fl] : -INFINITY;
    float m = v;
#pragma unroll
    for (int msk = 1; msk < 64; msk <<= 1) m = fmaxf(m, __shfl_xor(m, msk));
    float ex = act ? expf(v - m) : 0.f;
    float s = ex;
#pragma unroll
    for (int msk = 1; msk < 64; msk <<= 1) s += __shfl_xor(s, msk);
    if (act) out[(size_t)i * KCLS + lane] = v - m - logf(s);
}

extern "C" void kernel_launch(void* const* d_in, const int* in_sizes, int n_in,
                              void* d_out, int out_size, void* d_ws, size_t ws_size,
                              hipStream_t stream) {
    const float* x   = (const float*)d_in[0];
    const int*   ei  = (const int*)d_in[1];
    const float* W1  = (const float*)d_in[2];
    const float* b1  = (const float*)d_in[3];
    const float* g1  = (const float*)d_in[4];
    const float* be1 = (const float*)d_in[5];
    const float* W2  = (const float*)d_in[6];
    const float* b2  = (const float*)d_in[7];
    const float* g2  = (const float*)d_in[8];
    const float* be2 = (const float*)d_in[9];
    const float* W3  = (const float*)d_in[10];
    const float* b3  = (const float*)d_in[11];
    const int E = in_sizes[1] / 2;
    const int* srcI = ei;
    const int* dstI = ei + E;

    int*   cnt    = (int*)d_ws;
    float* dinv   = (float*)d_ws + NN;
    int*   rowptr = (int*)d_ws + 2 * NN;
    int*   bsum   = (int*)d_ws + 3 * NN;               // [SCAN_NB] padded to 512
    int*   btail  = (int*)d_ws + 3 * NN + 512;         // [NBKT] padded to 512
    int*   col    = (int*)d_ws + 3 * NN + 1024;
    float* bufA   = (float*)d_ws + 3 * NN + 1024 + E;  // 16B-aligned
    float* bufB   = bufA + (size_t)NN * 128;
    int*   ebuf   = (int*)bufB;                        // aliases bufB (dead until layer-1 gather)
    float* out    = (float*)d_out;

    dim3 blk(256);

    // ---- CSR build + norm ----
    hipMemsetAsync(cnt, 0, NN * sizeof(int), stream);
    k_count<<<(E + 255) / 256, blk, 0, stream>>>(dstI, cnt, E);
    k_dinv<<<(NN + 255) / 256, blk, 0, stream>>>(cnt, dinv);
    k_blocksum<<<SCAN_NB, SCAN_B, 0, stream>>>(cnt, bsum);
    k_scan_bsums<<<1, 128, 0, stream>>>(bsum);
    k_scan_final<<<SCAN_NB, SCAN_B, 0, stream>>>(cnt, bsum, rowptr);
    k_btail<<<(NBKT + 255) / 256, blk, 0, stream>>>(rowptr, btail);
    k_part<<<(E + PCHUNK - 1) / PCHUNK, blk, 0, stream>>>(srcI, dstI, btail, ebuf, E);
    k_fill2<<<NBKT, blk, 0, stream>>>(ebuf, btail, rowptr, col);

    const int gx = (NN + GTM - 1) / GTM;

    // ---- layer 1 ----
    {
        dim3 grid(gx, (KHID + GTN - 1) / GTN);
        k_gemm<<<grid, blk, 0, stream>>>(x, W1, bufA, NN, KHID, KHID);
    }
    k_gather_ln<<<(NN + 3) / 4, blk, 0, stream>>>(bufA, rowptr, col, dinv, b1, g1, be1, bufB);

    // ---- layer 2 ----
    {
        dim3 grid(gx, (KHID + GTN - 1) / GTN);
        k_gemm<<<grid, blk, 0, stream>>>(bufB, W2, bufA, NN, KHID, KHID);
    }
    k_gather_ln<<<(NN + 3) / 4, blk, 0, stream>>>(bufA, rowptr, col, dinv, b2, g2, be2, bufB);

    // ---- layer 3 ----
    float* h3 = bufA;   // NN*40
    {
        dim3 grid(gx, (KCLS + GTN - 1) / GTN);
        k_gemm<<<grid, blk, 0, stream>>>(bufB, W3, h3, NN, KHID, KCLS);
    }
    k_gather_lsm<<<(NN + 3) / 4, blk, 0, stream>>>(h3, rowptr, col, dinv, b3, out);
}

// Round 6
// 583.870 us; speedup vs baseline: 11.5042x; 1.1944x over previous
//
#include <hip/hip_runtime.h>
#include <math.h>

#define NN 100000
#define KHID 128
#define KCLS 40
#define LN_EPS 1e-5f
#define SCAN_B 1024
#define SCAN_NB ((NN + SCAN_B - 1) / SCAN_B)   // 98
#define NBKT ((NN + 255) >> 8)                 // 391 buckets of 256 nodes
#define PCHUNK 4096                            // edges per partition workgroup

typedef unsigned short bfu;

// float -> bf16 (RNE)
__device__ __forceinline__ bfu f2b(float f) {
    unsigned u = __float_as_uint(f);
    u += 0x7fffu + ((u >> 16) & 1u);
    return (bfu)(u >> 16);
}
__device__ __forceinline__ float b2f(bfu b) {
    return __uint_as_float(((unsigned)b) << 16);
}
// load 4 consecutive bf16 (8B) -> 4 floats
__device__ __forceinline__ void bf4(const bfu* p, float& x0, float& x1, float& x2, float& x3) {
    uint2 r = *(const uint2*)p;
    x0 = __uint_as_float(r.x << 16);
    x1 = __uint_as_float(r.x & 0xffff0000u);
    x2 = __uint_as_float(r.y << 16);
    x3 = __uint_as_float(r.y & 0xffff0000u);
}

// ======================= CSR build =======================
__global__ __launch_bounds__(256) void k_count(const int* __restrict__ dst,
                                               int* __restrict__ cnt, int E) {
    int e = blockIdx.x * 256 + threadIdx.x;
    if (e < E) atomicAdd(&cnt[dst[e]], 1);
}

__global__ __launch_bounds__(256) void k_dinv(const int* __restrict__ cnt,
                                              float* __restrict__ dinv) {
    int i = blockIdx.x * 256 + threadIdx.x;
    if (i < NN) dinv[i] = rsqrtf((float)(1 + cnt[i]));   // +1 self-loop
}

__global__ __launch_bounds__(SCAN_B) void k_blocksum(const int* __restrict__ cnt,
                                                     int* __restrict__ bsum) {
    __shared__ int wsum[16];
    int t = threadIdx.x, lane = t & 63, wv = t >> 6;
    int i = blockIdx.x * SCAN_B + t;
    int v = (i < NN) ? cnt[i] : 0;
#pragma unroll
    for (int m = 1; m < 64; m <<= 1) v += __shfl_xor(v, m);
    if (lane == 0) wsum[wv] = v;
    __syncthreads();
    if (t == 0) {
        int s = 0;
#pragma unroll
        for (int w = 0; w < 16; w++) s += wsum[w];
        bsum[blockIdx.x] = s;
    }
}

__global__ __launch_bounds__(128) void k_scan_bsums(int* __restrict__ bsum) {
    __shared__ int ws[2];
    int t = threadIdx.x, lane = t & 63, wv = t >> 6;
    int v = (t < SCAN_NB) ? bsum[t] : 0;
    int s = v;
#pragma unroll
    for (int off = 1; off < 64; off <<= 1) {
        int u = __shfl_up(s, off);
        if (lane >= off) s += u;
    }
    if (lane == 63) ws[wv] = s;
    __syncthreads();
    int add = (wv == 1) ? ws[0] : 0;
    if (t < SCAN_NB) bsum[t] = s + add - v;   // exclusive
}

__global__ __launch_bounds__(SCAN_B) void k_scan_final(const int* __restrict__ cnt,
                                                       const int* __restrict__ bsum,
                                                       int* __restrict__ rowptr) {
    __shared__ int wsum[16];
    int t = threadIdx.x, lane = t & 63, wv = t >> 6;
    int i = blockIdx.x * SCAN_B + t;
    int v = (i < NN) ? cnt[i] : 0;
    int s = v;
#pragma unroll
    for (int off = 1; off < 64; off <<= 1) {
        int u = __shfl_up(s, off);
        if (lane >= off) s += u;
    }
    if (lane == 63) wsum[wv] = s;
    __syncthreads();
    int woff = 0;
    for (int w = 0; w < wv; w++) woff += wsum[w];
    if (i < NN) rowptr[i] = bsum[blockIdx.x] + woff + s - v;
}

__global__ __launch_bounds__(256) void k_btail(const int* __restrict__ rowptr,
                                               int* __restrict__ btail) {
    int b = blockIdx.x * 256 + threadIdx.x;
    if (b < NBKT) btail[b] = rowptr[b << 8];
}

// pass 1: partition edges into dst-buckets; ebuf[pos] = (dst&255)<<20 | src
__global__ __launch_bounds__(256) void k_part(const int* __restrict__ srcA,
                                              const int* __restrict__ dstA,
                                              int* __restrict__ btail,
                                              int* __restrict__ ebuf, int E) {
    __shared__ int hist[NBKT];
    int tid = threadIdx.x;
    int base = blockIdx.x * PCHUNK;
    int sreg[PCHUNK / 256], dreg[PCHUNK / 256];

    for (int k = tid; k < NBKT; k += 256) hist[k] = 0;
    __syncthreads();
#pragma unroll
    for (int j = 0; j < PCHUNK / 256; j++) {
        int e = base + j * 256 + tid;
        if (e < E) {
            sreg[j] = srcA[e];
            int d = dstA[e];
            dreg[j] = d;
            atomicAdd(&hist[d >> 8], 1);
        } else dreg[j] = -1;
    }
    __syncthreads();
    for (int k = tid; k < NBKT; k += 256)
        hist[k] = atomicAdd(&btail[k], hist[k]);
    __syncthreads();
#pragma unroll
    for (int j = 0; j < PCHUNK / 256; j++) {
        int d = dreg[j];
        if (d >= 0) {
            int pos = atomicAdd(&hist[d >> 8], 1);
            ebuf[pos] = ((d & 255) << 20) | sreg[j];
        }
    }
}

// pass 2: within-bucket scatter (L2-resident region per workgroup)
__global__ __launch_bounds__(256) void k_fill2(const int* __restrict__ ebuf,
                                               const int* __restrict__ btail,
                                               int* __restrict__ rowptr,
                                               int* __restrict__ col) {
    int b = blockIdx.x;
    int bstart = (b == 0) ? 0 : btail[b - 1];
    int bend   = btail[b];
    int nb = b << 8;
    for (int e = bstart + threadIdx.x; e < bend; e += 256) {
        int p = ebuf[e];
        int d = nb + (p >> 20);
        int s = p & 0xFFFFF;
        int pos = atomicAdd(&rowptr[d], 1);
        col[pos] = s;
    }
}

// ======================= GEMM: 128x128 tile, 8x8 acc/thread, bf16 output ===========
#define GTM 128
#define GTN 128
#define GTK 16

__global__ __launch_bounds__(256) void k_gemm_b16(const float* __restrict__ X,
                                                  const float* __restrict__ W,
                                                  bfu* __restrict__ C,
                                                  int Nrows, int Kin, int Kout) {
    __shared__ float Xs[GTK][GTM + 4];
    __shared__ float Ws[GTK][GTN + 4];

    int tid  = threadIdx.x;
    int row0 = blockIdx.x * GTM;
    int col0 = blockIdx.y * GTN;
    int tr = tid >> 4;
    int tc = tid & 15;

    float acc[2][2][4][4];
#pragma unroll
    for (int a = 0; a < 2; a++)
#pragma unroll
        for (int b = 0; b < 2; b++)
#pragma unroll
            for (int i = 0; i < 4; i++)
#pragma unroll
                for (int j = 0; j < 4; j++) acc[a][b][i][j] = 0.f;

    for (int k0 = 0; k0 < Kin; k0 += GTK) {
        {
            int r  = tid >> 1;
            int kh = (tid & 1) * 8;
            int grow = row0 + r;
            float xv[8];
            if (grow < Nrows) {
                const float* xp = X + (size_t)grow * Kin + k0 + kh;
                float4 a = *(const float4*)xp;
                float4 b = *(const float4*)(xp + 4);
                xv[0]=a.x; xv[1]=a.y; xv[2]=a.z; xv[3]=a.w;
                xv[4]=b.x; xv[5]=b.y; xv[6]=b.z; xv[7]=b.w;
            } else {
#pragma unroll
                for (int i = 0; i < 8; i++) xv[i] = 0.f;
            }
#pragma unroll
            for (int i = 0; i < 8; i++) Xs[kh + i][r] = xv[i];
        }
        {
            int kw = tid >> 4;
            int n  = (tid & 15) * 8;
            const float* wp = W + (size_t)(k0 + kw) * Kout + col0 + n;
            if (col0 + n + 7 < Kout) {
                *(float4*)&Ws[kw][n]     = *(const float4*)wp;
                *(float4*)&Ws[kw][n + 4] = *(const float4*)(wp + 4);
            } else {
#pragma unroll
                for (int j = 0; j < 8; j++) {
                    int c = col0 + n + j;
                    Ws[kw][n + j] = (c < Kout) ? wp[j] : 0.f;
                }
            }
        }
        __syncthreads();
#pragma unroll
        for (int k = 0; k < GTK; k++) {
            float4 a0 = *(const float4*)&Xs[k][tr * 4];
            float4 a1 = *(const float4*)&Xs[k][64 + tr * 4];
            float4 b0 = *(const float4*)&Ws[k][tc * 4];
            float4 b1 = *(const float4*)&Ws[k][64 + tc * 4];
            float ar[2][4] = {{a0.x,a0.y,a0.z,a0.w},{a1.x,a1.y,a1.z,a1.w}};
            float br[2][4] = {{b0.x,b0.y,b0.z,b0.w},{b1.x,b1.y,b1.z,b1.w}};
#pragma unroll
            for (int a = 0; a < 2; a++)
#pragma unroll
                for (int b = 0; b < 2; b++)
#pragma unroll
                    for (int i = 0; i < 4; i++)
#pragma unroll
                        for (int j = 0; j < 4; j++)
                            acc[a][b][i][j] += ar[a][i] * br[b][j];
        }
        __syncthreads();
    }
#pragma unroll
    for (int a = 0; a < 2; a++)
#pragma unroll
        for (int i = 0; i < 4; i++) {
            int grow = row0 + a * 64 + tr * 4 + i;
            if (grow >= Nrows) continue;
#pragma unroll
            for (int b = 0; b < 2; b++) {
                int gcol = col0 + b * 64 + tc * 4;
                if (gcol + 3 < Kout) {
                    ushort4 v;
                    v.x = f2b(acc[a][b][i][0]); v.y = f2b(acc[a][b][i][1]);
                    v.z = f2b(acc[a][b][i][2]); v.w = f2b(acc[a][b][i][3]);
                    *(ushort4*)(C + (size_t)grow * Kout + gcol) = v;
                } else {
#pragma unroll
                    for (int j = 0; j < 4; j++)
                        if (gcol + j < Kout) C[(size_t)grow * Kout + gcol + j] = f2b(acc[a][b][i][j]);
                }
            }
        }
}

// ======= fused gather(bf16 h) + bias + LN + ReLU (K=128), one wave per node =======
__global__ __launch_bounds__(256) void k_gather_ln(const bfu* __restrict__ hb,
                                                   const int* __restrict__ rend,
                                                   const int* __restrict__ col,
                                                   const float* __restrict__ dinv,
                                                   const float* __restrict__ bias,
                                                   const float* __restrict__ gamma,
                                                   const float* __restrict__ beta,
                                                   float* __restrict__ out) {
    int wave = threadIdx.x >> 6;
    int lane = threadIdx.x & 63;
    int i = blockIdx.x * 4 + wave;
    if (i >= NN) return;
    int start = (i == 0) ? 0 : rend[i - 1];
    int end   = rend[i];
    float di = dinv[i];
    int half = lane >> 5;
    int fl   = (lane & 31) * 4;

    float ax = 0.f, ay = 0.f, az = 0.f, aw = 0.f;
    if (half == 0) {   // self-loop
        float v0, v1, v2, v3;
        bf4(hb + (size_t)i * 128 + fl, v0, v1, v2, v3);
        float w = di * di;
        ax = w * v0; ay = w * v1; az = w * v2; aw = w * v3;
    }

    for (int b = start; b < end; b += 64) {
        int n = end - b; if (n > 64) n = 64;
        int c = 0; float w = 0.f;
        if (lane < n) { c = col[b + lane]; w = dinv[c] * di; }
        int tmax = (n + 1) >> 1;
        int t = 0;
        for (; t + 4 <= tmax; t += 4) {
            int e0 = 2 * t + half;
            int c0 = __shfl(c, e0),     c1 = __shfl(c, e0 + 2);
            int c2 = __shfl(c, e0 + 4), c3 = __shfl(c, e0 + 6);
            float w0 = __shfl(w, e0),     w1 = __shfl(w, e0 + 2);
            float w2 = __shfl(w, e0 + 4), w3 = __shfl(w, e0 + 6);
            float p0, p1, p2, p3, q0, q1, q2, q3;
            float r0, r1, r2, r3, s0, s1, s2, s3;
            bf4(hb + (size_t)c0 * 128 + fl, p0, p1, p2, p3);
            bf4(hb + (size_t)c1 * 128 + fl, q0, q1, q2, q3);
            bf4(hb + (size_t)c2 * 128 + fl, r0, r1, r2, r3);
            bf4(hb + (size_t)c3 * 128 + fl, s0, s1, s2, s3);
            ax += w0 * p0; ay += w0 * p1; az += w0 * p2; aw += w0 * p3;
            ax += w1 * q0; ay += w1 * q1; az += w1 * q2; aw += w1 * q3;
            ax += w2 * r0; ay += w2 * r1; az += w2 * r2; aw += w2 * r3;
            ax += w3 * s0; ay += w3 * s1; az += w3 * s2; aw += w3 * s3;
        }
        for (; t < tmax; t++) {
            int e0 = 2 * t + half;
            int c0 = __shfl(c, e0);
            float w0 = __shfl(w, e0);
            float p0, p1, p2, p3;
            bf4(hb + (size_t)c0 * 128 + fl, p0, p1, p2, p3);
            ax += w0 * p0; ay += w0 * p1; az += w0 * p2; aw += w0 * p3;
        }
    }
    ax += __shfl_xor(ax, 32); ay += __shfl_xor(ay, 32);
    az += __shfl_xor(az, 32); aw += __shfl_xor(aw, 32);

    float4 bb = *(const float4*)(bias + fl);
    float x0 = ax + bb.x, x1 = ay + bb.y, x2 = az + bb.z, x3 = aw + bb.w;

    float s = x0 + x1 + x2 + x3;
#pragma unroll
    for (int m = 1; m < 64; m <<= 1) s += __shfl_xor(s, m);
    float mu = s * (1.f / 256.f);
    float d0 = x0 - mu, d1 = x1 - mu, d2 = x2 - mu, d3 = x3 - mu;
    float vs = d0 * d0 + d1 * d1 + d2 * d2 + d3 * d3;
#pragma unroll
    for (int m = 1; m < 64; m <<= 1) vs += __shfl_xor(vs, m);
    float inv = rsqrtf(vs * (1.f / 256.f) + LN_EPS);
    if (half == 0) {
        float4 gg = *(const float4*)(gamma + fl);
        float4 ee = *(const float4*)(beta + fl);
        float4 o;
        o.x = fmaxf(d0 * inv * gg.x + ee.x, 0.f);
        o.y = fmaxf(d1 * inv * gg.y + ee.y, 0.f);
        o.z = fmaxf(d2 * inv * gg.z + ee.z, 0.f);
        o.w = fmaxf(d3 * inv * gg.w + ee.w, 0.f);
        *(float4*)(out + (size_t)i * 128 + fl) = o;
    }
}

// ======= fused gather(bf16 h) + bias + log_softmax (K=40), one wave per node =======
__global__ __launch_bounds__(256) void k_gather_lsm(const bfu* __restrict__ hb,
                                                    const int* __restrict__ rend,
                                                    const int* __restrict__ col,
                                                    const float* __restrict__ dinv,
                                                    const float* __restrict__ b3,
                                                    float* __restrict__ out) {
    int wave = threadIdx.x >> 6;
    int lane = threadIdx.x & 63;
    int i = blockIdx.x * 4 + wave;
    if (i >= NN) return;
    int start = (i == 0) ? 0 : rend[i - 1];
    int end   = rend[i];
    float di = dinv[i];
    bool act = lane < KCLS;
    int  fl  = act ? lane : 0;

    float acc = act ? di * di * b2f(hb[(size_t)i * KCLS + fl]) : 0.f;

    for (int b = start; b < end; b += 64) {
        int n = end - b; if (n > 64) n = 64;
        int c = 0; float w = 0.f;
        if (lane < n) { c = col[b + lane]; w = dinv[c] * di; }
        int t = 0;
        for (; t + 4 <= n; t += 4) {
            int c0 = __shfl(c, t),     c1 = __shfl(c, t + 1);
            int c2 = __shfl(c, t + 2), c3 = __shfl(c, t + 3);
            float w0 = __shfl(w, t),     w1 = __shfl(w, t + 1);
            float w2 = __shfl(w, t + 2), w3 = __shfl(w, t + 3);
            float v0 = b2f(hb[(size_t)c0 * KCLS + fl]);
            float v1 = b2f(hb[(size_t)c1 * KCLS + fl]);
            float v2 = b2f(hb[(size_t)c2 * KCLS + fl]);
            float v3 = b2f(hb[(size_t)c3 * KCLS + fl]);
            acc += w0 * v0 + w1 * v1 + w2 * v2 + w3 * v3;
        }
        for (; t < n; t++) {
            int c0 = __shfl(c, t);
            float w0 = __shfl(w, t);
            acc += w0 * b2f(hb[(size_t)c0 * KCLS + fl]);
        }
    }
    float v = act ? acc + b3[fl] : -INFINITY;
    float m = v;
#pragma unroll
    for (int msk = 1; msk < 64; msk <<= 1) m = fmaxf(m, __shfl_xor(m, msk));
    float ex = act ? expf(v - m) : 0.f;
    float s = ex;
#pragma unroll
    for (int msk = 1; msk < 64; msk <<= 1) s += __shfl_xor(s, msk);
    if (act) out[(size_t)i * KCLS + lane] = v - m - logf(s);
}

extern "C" void kernel_launch(void* const* d_in, const int* in_sizes, int n_in,
                              void* d_out, int out_size, void* d_ws, size_t ws_size,
                              hipStream_t stream) {
    const float* x   = (const float*)d_in[0];
    const int*   ei  = (const int*)d_in[1];
    const float* W1  = (const float*)d_in[2];
    const float* b1  = (const float*)d_in[3];
    const float* g1  = (const float*)d_in[4];
    const float* be1 = (const float*)d_in[5];
    const float* W2  = (const float*)d_in[6];
    const float* b2  = (const float*)d_in[7];
    const float* g2  = (const float*)d_in[8];
    const float* be2 = (const float*)d_in[9];
    const float* W3  = (const float*)d_in[10];
    const float* b3  = (const float*)d_in[11];
    const int E = in_sizes[1] / 2;
    const int* srcI = ei;
    const int* dstI = ei + E;

    // workspace (float-granularity offsets):
    // [cnt NN][dinv NN][rowptr NN][bsum 512][btail 512][col E][hbuf NN*64][fbuf NN*128]
    int*   cnt    = (int*)d_ws;
    float* dinv   = (float*)d_ws + NN;
    int*   rowptr = (int*)d_ws + 2 * NN;
    int*   bsum   = (int*)d_ws + 3 * NN;
    int*   btail  = (int*)d_ws + 3 * NN + 512;
    int*   col    = (int*)d_ws + 3 * NN + 1024;
    bfu*   hbuf   = (bfu*)((float*)d_ws + 3 * NN + 1024 + E);      // NN*128 bf16
    float* fbuf   = (float*)d_ws + 3 * NN + 1024 + E + (size_t)NN * 64;
    int*   ebuf   = (int*)fbuf;   // aliases fbuf (dead until first gather output)
    float* out    = (float*)d_out;

    dim3 blk(256);

    // ---- CSR build + norm ----
    hipMemsetAsync(cnt, 0, NN * sizeof(int), stream);
    k_count<<<(E + 255) / 256, blk, 0, stream>>>(dstI, cnt, E);
    k_dinv<<<(NN + 255) / 256, blk, 0, stream>>>(cnt, dinv);
    k_blocksum<<<SCAN_NB, SCAN_B, 0, stream>>>(cnt, bsum);
    k_scan_bsums<<<1, 128, 0, stream>>>(bsum);
    k_scan_final<<<SCAN_NB, SCAN_B, 0, stream>>>(cnt, bsum, rowptr);
    k_btail<<<(NBKT + 255) / 256, blk, 0, stream>>>(rowptr, btail);
    k_part<<<(E + PCHUNK - 1) / PCHUNK, blk, 0, stream>>>(srcI, dstI, btail, ebuf, E);
    k_fill2<<<NBKT, blk, 0, stream>>>(ebuf, btail, rowptr, col);

    const int gx = (NN + GTM - 1) / GTM;

    // ---- layer 1: x @ W1 -> hbuf (bf16); gather+LN -> fbuf ----
    {
        dim3 grid(gx, (KHID + GTN - 1) / GTN);
        k_gemm_b16<<<grid, blk, 0, stream>>>(x, W1, hbuf, NN, KHID, KHID);
    }
    k_gather_ln<<<(NN + 3) / 4, blk, 0, stream>>>(hbuf, rowptr, col, dinv, b1, g1, be1, fbuf);

    // ---- layer 2: fbuf @ W2 -> hbuf (bf16); gather+LN -> fbuf ----
    {
        dim3 grid(gx, (KHID + GTN - 1) / GTN);
        k_gemm_b16<<<grid, blk, 0, stream>>>(fbuf, W2, hbuf, NN, KHID, KHID);
    }
    k_gather_ln<<<(NN + 3) / 4, blk, 0, stream>>>(hbuf, rowptr, col, dinv, b2, g2, be2, fbuf);

    // ---- layer 3: fbuf @ W3 -> hbuf (bf16, NN*40); gather+log_softmax -> out ----
    {
        dim3 grid(gx, (KCLS + GTN - 1) / GTN);
        k_gemm_b16<<<grid, blk, 0, stream>>>(fbuf, W3, hbuf, NN, KHID, KCLS);
    }
    k_gather_lsm<<<(NN + 3) / 4, blk, 0, stream>>>(hbuf, rowptr, col, dinv, b3, out);
}

// Round 7
// 489.975 us; speedup vs baseline: 13.7088x; 1.1916x over previous
//
#include <hip/hip_runtime.h>
#include <math.h>

#define NN 100000
#define KHID 128
#define KCLS 40
#define LN_EPS 1e-5f
#define SCAN_B 1024
#define SCAN_NB ((NN + SCAN_B - 1) / SCAN_B)   // 98
#define NBKT ((NN + 255) >> 8)                 // 391 buckets of 256 nodes
#define PCHUNK 4096                            // edges per partition workgroup

typedef unsigned short bfu;
typedef __attribute__((ext_vector_type(8))) short short8;
typedef __attribute__((ext_vector_type(4))) float floatx4;

// float -> bf16 (RNE)
__device__ __forceinline__ bfu f2b(float f) {
    unsigned u = __float_as_uint(f);
    u += 0x7fffu + ((u >> 16) & 1u);
    return (bfu)(u >> 16);
}
__device__ __forceinline__ float b2f(bfu b) {
    return __uint_as_float(((unsigned)b) << 16);
}
__device__ __forceinline__ unsigned pack2(float a, float b) {
    return (unsigned)f2b(a) | ((unsigned)f2b(b) << 16);
}
// load 4 consecutive bf16 (8B) -> 4 floats
__device__ __forceinline__ void bf4(const bfu* p, float& x0, float& x1, float& x2, float& x3) {
    uint2 r = *(const uint2*)p;
    x0 = __uint_as_float(r.x << 16);
    x1 = __uint_as_float(r.x & 0xffff0000u);
    x2 = __uint_as_float(r.y << 16);
    x3 = __uint_as_float(r.y & 0xffff0000u);
}

// ======================= CSR build =======================
__global__ __launch_bounds__(256) void k_count(const int* __restrict__ dst,
                                               int* __restrict__ cnt, int E) {
    int e = blockIdx.x * 256 + threadIdx.x;
    if (e < E) atomicAdd(&cnt[dst[e]], 1);
}

__global__ __launch_bounds__(256) void k_dinv(const int* __restrict__ cnt,
                                              float* __restrict__ dinv) {
    int i = blockIdx.x * 256 + threadIdx.x;
    if (i < NN) dinv[i] = rsqrtf((float)(1 + cnt[i]));   // +1 self-loop
}

__global__ __launch_bounds__(SCAN_B) void k_blocksum(const int* __restrict__ cnt,
                                                     int* __restrict__ bsum) {
    __shared__ int wsum[16];
    int t = threadIdx.x, lane = t & 63, wv = t >> 6;
    int i = blockIdx.x * SCAN_B + t;
    int v = (i < NN) ? cnt[i] : 0;
#pragma unroll
    for (int m = 1; m < 64; m <<= 1) v += __shfl_xor(v, m);
    if (lane == 0) wsum[wv] = v;
    __syncthreads();
    if (t == 0) {
        int s = 0;
#pragma unroll
        for (int w = 0; w < 16; w++) s += wsum[w];
        bsum[blockIdx.x] = s;
    }
}

__global__ __launch_bounds__(128) void k_scan_bsums(int* __restrict__ bsum) {
    __shared__ int ws[2];
    int t = threadIdx.x, lane = t & 63, wv = t >> 6;
    int v = (t < SCAN_NB) ? bsum[t] : 0;
    int s = v;
#pragma unroll
    for (int off = 1; off < 64; off <<= 1) {
        int u = __shfl_up(s, off);
        if (lane >= off) s += u;
    }
    if (lane == 63) ws[wv] = s;
    __syncthreads();
    int add = (wv == 1) ? ws[0] : 0;
    if (t < SCAN_NB) bsum[t] = s + add - v;   // exclusive
}

__global__ __launch_bounds__(SCAN_B) void k_scan_final(const int* __restrict__ cnt,
                                                       const int* __restrict__ bsum,
                                                       int* __restrict__ rowptr) {
    __shared__ int wsum[16];
    int t = threadIdx.x, lane = t & 63, wv = t >> 6;
    int i = blockIdx.x * SCAN_B + t;
    int v = (i < NN) ? cnt[i] : 0;
    int s = v;
#pragma unroll
    for (int off = 1; off < 64; off <<= 1) {
        int u = __shfl_up(s, off);
        if (lane >= off) s += u;
    }
    if (lane == 63) wsum[wv] = s;
    __syncthreads();
    int woff = 0;
    for (int w = 0; w < wv; w++) woff += wsum[w];
    if (i < NN) rowptr[i] = bsum[blockIdx.x] + woff + s - v;
}

__global__ __launch_bounds__(256) void k_btail(const int* __restrict__ rowptr,
                                               int* __restrict__ btail) {
    int b = blockIdx.x * 256 + threadIdx.x;
    if (b < NBKT) btail[b] = rowptr[b << 8];
}

// pass 1: partition edges into dst-buckets; ebuf[pos] = (dst&255)<<20 | src
__global__ __launch_bounds__(256) void k_part(const int* __restrict__ srcA,
                                              const int* __restrict__ dstA,
                                              int* __restrict__ btail,
                                              int* __restrict__ ebuf, int E) {
    __shared__ int hist[NBKT];
    int tid = threadIdx.x;
    int base = blockIdx.x * PCHUNK;
    int sreg[PCHUNK / 256], dreg[PCHUNK / 256];

    for (int k = tid; k < NBKT; k += 256) hist[k] = 0;
    __syncthreads();
#pragma unroll
    for (int j = 0; j < PCHUNK / 256; j++) {
        int e = base + j * 256 + tid;
        if (e < E) {
            sreg[j] = srcA[e];
            int d = dstA[e];
            dreg[j] = d;
            atomicAdd(&hist[d >> 8], 1);
        } else dreg[j] = -1;
    }
    __syncthreads();
    for (int k = tid; k < NBKT; k += 256)
        hist[k] = atomicAdd(&btail[k], hist[k]);
    __syncthreads();
#pragma unroll
    for (int j = 0; j < PCHUNK / 256; j++) {
        int d = dreg[j];
        if (d >= 0) {
            int pos = atomicAdd(&hist[d >> 8], 1);
            ebuf[pos] = ((d & 255) << 20) | sreg[j];
        }
    }
}

// pass 2: within-bucket scatter (L2-resident region per workgroup)
__global__ __launch_bounds__(256) void k_fill2(const int* __restrict__ ebuf,
                                               const int* __restrict__ btail,
                                               int* __restrict__ rowptr,
                                               int* __restrict__ col) {
    int b = blockIdx.x;
    int bstart = (b == 0) ? 0 : btail[b - 1];
    int bend   = btail[b];
    int nb = b << 8;
    for (int e = bstart + threadIdx.x; e < bend; e += 256) {
        int p = ebuf[e];
        int d = nb + (p >> 20);
        int s = p & 0xFFFFF;
        int pos = atomicAdd(&rowptr[d], 1);
        col[pos] = s;
    }
}

// ======================= fp32 -> bf16 cast (x) =======================
__global__ __launch_bounds__(256) void k_cast(const float* __restrict__ X,
                                              bfu* __restrict__ Y, int n8) {
    int i = blockIdx.x * 256 + threadIdx.x;   // 8 elements per thread
    if (i < n8) {
        const float4* p = (const float4*)(X + (size_t)i * 8);
        float4 a = p[0], b = p[1];
        uint4 v;
        v.x = pack2(a.x, a.y); v.y = pack2(a.z, a.w);
        v.z = pack2(b.x, b.y); v.w = pack2(b.z, b.w);
        *(uint4*)(Y + (size_t)i * 8) = v;
    }
}

// ======================= MFMA GEMM: C[M,KOUT] = A[M,128](bf16) @ W[128,KOUT](f32) =====
// single-shot K=128 in LDS; 128-row tile per block; 4 waves, each 32 rows x NPAD cols
template <int KOUT, int NPAD>
__global__ __launch_bounds__(256) void k_gemm_mfma(const bfu* __restrict__ A,
                                                   const float* __restrict__ W,
                                                   bfu* __restrict__ C, int M) {
    constexpr int NT = NPAD / 16;
    __shared__ bfu As[128][136];    // [m][k], +8 pad
    __shared__ bfu Ws[NPAD][136];   // [n][k] transposed, +8 pad

    int tid  = threadIdx.x;
    int row0 = blockIdx.x * 128;

    // ---- stage A (32 KB tile), flat fully-coalesced 16 B/lane ----
    {
        const char* Ab = (const char*)(A + (size_t)row0 * 128);
#pragma unroll
        for (int c2 = 0; c2 < 8; c2++) {
            int off = c2 * 4096 + tid * 16;    // byte offset in 32 KB tile
            int r   = off >> 8;                // 256 B per logical row
            int kb  = off & 255;
            uint4 v = *(const uint4*)(Ab + off);
            *(uint4*)((char*)&As[0][0] + r * 272 + kb) = v;
        }
    }
    // ---- stage W transposed + cvt bf16 ----
    if constexpr (KOUT == 128) {
        int n = tid & 127, kh = (tid >> 7) * 64;
#pragma unroll
        for (int kk = 0; kk < 64; kk += 8) {
            float f[8];
#pragma unroll
            for (int i = 0; i < 8; i++) f[i] = W[(size_t)(kh + kk + i) * 128 + n];
            uint4 v;
            v.x = pack2(f[0], f[1]); v.y = pack2(f[2], f[3]);
            v.z = pack2(f[4], f[5]); v.w = pack2(f[6], f[7]);
            *(uint4*)&Ws[n][kh + kk] = v;
        }
    } else {
        int n = tid & 63, kh = (tid >> 6) * 32;
        if (n < NPAD) {
#pragma unroll
            for (int kk = 0; kk < 32; kk += 8) {
                float f[8];
#pragma unroll
                for (int i = 0; i < 8; i++)
                    f[i] = (n < KOUT) ? W[(size_t)(kh + kk + i) * KOUT + n] : 0.f;
                uint4 v;
                v.x = pack2(f[0], f[1]); v.y = pack2(f[2], f[3]);
                v.z = pack2(f[4], f[5]); v.w = pack2(f[6], f[7]);
                *(uint4*)&Ws[n][kh + kk] = v;
            }
        }
    }
    __syncthreads();

    int w = tid >> 6, lane = tid & 63;
    int quad = lane >> 4, mrow = lane & 15;

    floatx4 acc[2][NT];
#pragma unroll
    for (int mt = 0; mt < 2; mt++)
#pragma unroll
        for (int nt = 0; nt < NT; nt++) acc[mt][nt] = (floatx4){0.f, 0.f, 0.f, 0.f};

#pragma unroll
    for (int ks = 0; ks < 4; ks++) {
        int ko = ks * 32 + quad * 8;
        short8 af[2];
#pragma unroll
        for (int mt = 0; mt < 2; mt++)
            af[mt] = *(const short8*)&As[16 * (2 * w + mt) + mrow][ko];
#pragma unroll
        for (int nt = 0; nt < NT; nt++) {
            short8 bf = *(const short8*)&Ws[16 * nt + mrow][ko];
#pragma unroll
            for (int mt = 0; mt < 2; mt++)
                acc[mt][nt] = __builtin_amdgcn_mfma_f32_16x16x32_bf16(af[mt], bf, acc[mt][nt], 0, 0, 0);
        }
    }

    // epilogue: C/D layout col=lane&15, row=quad*4+reg
#pragma unroll
    for (int mt = 0; mt < 2; mt++) {
        int rbase = row0 + 16 * (2 * w + mt) + quad * 4;
#pragma unroll
        for (int nt = 0; nt < NT; nt++) {
            int cidx = 16 * nt + mrow;
            if (KOUT != NPAD && cidx >= KOUT) continue;
#pragma unroll
            for (int r = 0; r < 4; r++) {
                int row = rbase + r;
                if (row < M) C[(size_t)row * KOUT + cidx] = f2b(acc[mt][nt][r]);
            }
        }
    }
}

// ======= fused gather(bf16 h) + bias + LN + ReLU (K=128) -> bf16 out =======
__global__ __launch_bounds__(256) void k_gather_ln(const bfu* __restrict__ hb,
                                                   const int* __restrict__ rend,
                                                   const int* __restrict__ col,
                                                   const float* __restrict__ dinv,
                                                   const float* __restrict__ bias,
                                                   const float* __restrict__ gamma,
                                                   const float* __restrict__ beta,
                                                   bfu* __restrict__ outb) {
    int wave = threadIdx.x >> 6;
    int lane = threadIdx.x & 63;
    int i = blockIdx.x * 4 + wave;
    if (i >= NN) return;
    int start = (i == 0) ? 0 : rend[i - 1];
    int end   = rend[i];
    float di = dinv[i];
    int half = lane >> 5;
    int fl   = (lane & 31) * 4;

    float ax = 0.f, ay = 0.f, az = 0.f, aw = 0.f;
    if (half == 0) {   // self-loop
        float v0, v1, v2, v3;
        bf4(hb + (size_t)i * 128 + fl, v0, v1, v2, v3);
        float w = di * di;
        ax = w * v0; ay = w * v1; az = w * v2; aw = w * v3;
    }

    for (int b = start; b < end; b += 64) {
        int n = end - b; if (n > 64) n = 64;
        int c = 0; float w = 0.f;
        if (lane < n) { c = col[b + lane]; w = dinv[c] * di; }
        int tmax = (n + 1) >> 1;
        int t = 0;
        for (; t + 4 <= tmax; t += 4) {
            int e0 = 2 * t + half;
            int c0 = __shfl(c, e0),     c1 = __shfl(c, e0 + 2);
            int c2 = __shfl(c, e0 + 4), c3 = __shfl(c, e0 + 6);
            float w0 = __shfl(w, e0),     w1 = __shfl(w, e0 + 2);
            float w2 = __shfl(w, e0 + 4), w3 = __shfl(w, e0 + 6);
            float p0, p1, p2, p3, q0, q1, q2, q3;
            float r0, r1, r2, r3, s0, s1, s2, s3;
            bf4(hb + (size_t)c0 * 128 + fl, p0, p1, p2, p3);
            bf4(hb + (size_t)c1 * 128 + fl, q0, q1, q2, q3);
            bf4(hb + (size_t)c2 * 128 + fl, r0, r1, r2, r3);
            bf4(hb + (size_t)c3 * 128 + fl, s0, s1, s2, s3);
            ax += w0 * p0; ay += w0 * p1; az += w0 * p2; aw += w0 * p3;
            ax += w1 * q0; ay += w1 * q1; az += w1 * q2; aw += w1 * q3;
            ax += w2 * r0; ay += w2 * r1; az += w2 * r2; aw += w2 * r3;
            ax += w3 * s0; ay += w3 * s1; az += w3 * s2; aw += w3 * s3;
        }
        for (; t < tmax; t++) {
            int e0 = 2 * t + half;
            int c0 = __shfl(c, e0);
            float w0 = __shfl(w, e0);
            float p0, p1, p2, p3;
            bf4(hb + (size_t)c0 * 128 + fl, p0, p1, p2, p3);
            ax += w0 * p0; ay += w0 * p1; az += w0 * p2; aw += w0 * p3;
        }
    }
    ax += __shfl_xor(ax, 32); ay += __shfl_xor(ay, 32);
    az += __shfl_xor(az, 32); aw += __shfl_xor(aw, 32);

    float4 bb = *(const float4*)(bias + fl);
    float x0 = ax + bb.x, x1 = ay + bb.y, x2 = az + bb.z, x3 = aw + bb.w;

    float s = x0 + x1 + x2 + x3;
#pragma unroll
    for (int m = 1; m < 64; m <<= 1) s += __shfl_xor(s, m);
    float mu = s * (1.f / 256.f);
    float d0 = x0 - mu, d1 = x1 - mu, d2 = x2 - mu, d3 = x3 - mu;
    float vs = d0 * d0 + d1 * d1 + d2 * d2 + d3 * d3;
#pragma unroll
    for (int m = 1; m < 64; m <<= 1) vs += __shfl_xor(vs, m);
    float inv = rsqrtf(vs * (1.f / 256.f) + LN_EPS);
    if (half == 0) {
        float4 gg = *(const float4*)(gamma + fl);
        float4 ee = *(const float4*)(beta + fl);
        ushort4 o;
        o.x = f2b(fmaxf(d0 * inv * gg.x + ee.x, 0.f));
        o.y = f2b(fmaxf(d1 * inv * gg.y + ee.y, 0.f));
        o.z = f2b(fmaxf(d2 * inv * gg.z + ee.z, 0.f));
        o.w = f2b(fmaxf(d3 * inv * gg.w + ee.w, 0.f));
        *(ushort4*)(outb + (size_t)i * 128 + fl) = o;
    }
}

// ======= fused gather(bf16 h) + bias + log_softmax (K=40) =======
__global__ __launch_bounds__(256) void k_gather_lsm(const bfu* __restrict__ hb,
                                                    const int* __restrict__ rend,
                                                    const int* __restrict__ col,
                                                    const float* __restrict__ dinv,
                                                    const float* __restrict__ b3,
                                                    float* __restrict__ out) {
    int wave = threadIdx.x >> 6;
    int lane = threadIdx.x & 63;
    int i = blockIdx.x * 4 + wave;
    if (i >= NN) return;
    int start = (i == 0) ? 0 : rend[i - 1];
    int end   = rend[i];
    float di = dinv[i];
    bool act = lane < KCLS;
    int  fl  = act ? lane : 0;

    float acc = act ? di * di * b2f(hb[(size_t)i * KCLS + fl]) : 0.f;

    for (int b = start; b < end; b += 64) {
        int n = end - b; if (n > 64) n = 64;
        int c = 0; float w = 0.f;
        if (lane < n) { c = col[b + lane]; w = dinv[c] * di; }
        int t = 0;
        for (; t + 4 <= n; t += 4) {
            int c0 = __shfl(c, t),     c1 = __shfl(c, t + 1);
            int c2 = __shfl(c, t + 2), c3 = __shfl(c, t + 3);
            float w0 = __shfl(w, t),     w1 = __shfl(w, t + 1);
            float w2 = __shfl(w, t + 2), w3 = __shfl(w, t + 3);
            float v0 = b2f(hb[(size_t)c0 * KCLS + fl]);
            float v1 = b2f(hb[(size_t)c1 * KCLS + fl]);
            float v2 = b2f(hb[(size_t)c2 * KCLS + fl]);
            float v3 = b2f(hb[(size_t)c3 * KCLS + fl]);
            acc += w0 * v0 + w1 * v1 + w2 * v2 + w3 * v3;
        }
        for (; t < n; t++) {
            int c0 = __shfl(c, t);
            float w0 = __shfl(w, t);
            acc += w0 * b2f(hb[(size_t)c0 * KCLS + fl]);
        }
    }
    float v = act ? acc + b3[fl] : -INFINITY;
    float m = v;
#pragma unroll
    for (int msk = 1; msk < 64; msk <<= 1) m = fmaxf(m, __shfl_xor(m, msk));
    float ex = act ? expf(v - m) : 0.f;
    float s = ex;
#pragma unroll
    for (int msk = 1; msk < 64; msk <<= 1) s += __shfl_xor(s, msk);
    if (act) out[(size_t)i * KCLS + lane] = v - m - logf(s);
}

extern "C" void kernel_launch(void* const* d_in, const int* in_sizes, int n_in,
                              void* d_out, int out_size, void* d_ws, size_t ws_size,
                              hipStream_t stream) {
    const float* x   = (const float*)d_in[0];
    const int*   ei  = (const int*)d_in[1];
    const float* W1  = (const float*)d_in[2];
    const float* b1  = (const float*)d_in[3];
    const float* g1  = (const float*)d_in[4];
    const float* be1 = (const float*)d_in[5];
    const float* W2  = (const float*)d_in[6];
    const float* b2  = (const float*)d_in[7];
    const float* g2  = (const float*)d_in[8];
    const float* be2 = (const float*)d_in[9];
    const float* W3  = (const float*)d_in[10];
    const float* b3  = (const float*)d_in[11];
    const int E = in_sizes[1] / 2;
    const int* srcI = ei;
    const int* dstI = ei + E;

    // workspace (float units):
    // [cnt NN][dinv NN][rowptr NN][bsum 512][btail 512][xb NN*64][hbuf NN*64][lbuf NN*64][col E]
    // (xb/hbuf/lbuf are NN*128 bf16 each; col last so GEMM A-tile overrun of the
    //  final 128-row block reads allocated memory; ebuf aliases xb, dead before k_cast)
    int*   cnt    = (int*)d_ws;
    float* dinv   = (float*)d_ws + NN;
    int*   rowptr = (int*)d_ws + 2 * NN;
    int*   bsum   = (int*)d_ws + 3 * NN;
    int*   btail  = (int*)d_ws + 3 * NN + 512;
    float* base   = (float*)d_ws + 3 * NN + 1024;
    bfu*   xb     = (bfu*)base;                         // NN*128 bf16
    bfu*   hbuf   = (bfu*)(base + (size_t)NN * 64);     // NN*128 bf16
    bfu*   lbuf   = (bfu*)(base + (size_t)NN * 128);    // NN*128 bf16
    int*   col    = (int*)(base + (size_t)NN * 192);    // E ints
    int*   ebuf   = (int*)xb;                           // aliases xb
    float* out    = (float*)d_out;

    dim3 blk(256);

    // ---- CSR build + norm ----
    hipMemsetAsync(cnt, 0, NN * sizeof(int), stream);
    k_count<<<(E + 255) / 256, blk, 0, stream>>>(dstI, cnt, E);
    k_dinv<<<(NN + 255) / 256, blk, 0, stream>>>(cnt, dinv);
    k_blocksum<<<SCAN_NB, SCAN_B, 0, stream>>>(cnt, bsum);
    k_scan_bsums<<<1, 128, 0, stream>>>(bsum);
    k_scan_final<<<SCAN_NB, SCAN_B, 0, stream>>>(cnt, bsum, rowptr);
    k_btail<<<(NBKT + 255) / 256, blk, 0, stream>>>(rowptr, btail);
    k_part<<<(E + PCHUNK - 1) / PCHUNK, blk, 0, stream>>>(srcI, dstI, btail, ebuf, E);
    k_fill2<<<NBKT, blk, 0, stream>>>(ebuf, btail, rowptr, col);

    // ---- cast x -> bf16 (after fill2: ebuf aliases xb) ----
    k_cast<<<(NN * 16 + 255) / 256, blk, 0, stream>>>(x, xb, NN * 16);

    const int gx = (NN + 127) / 128;   // 782

    // ---- layer 1 ----
    k_gemm_mfma<128, 128><<<gx, blk, 0, stream>>>(xb, W1, hbuf, NN);
    k_gather_ln<<<(NN + 3) / 4, blk, 0, stream>>>(hbuf, rowptr, col, dinv, b1, g1, be1, lbuf);

    // ---- layer 2 ----
    k_gemm_mfma<128, 128><<<gx, blk, 0, stream>>>(lbuf, W2, hbuf, NN);
    k_gather_ln<<<(NN + 3) / 4, blk, 0, stream>>>(hbuf, rowptr, col, dinv, b2, g2, be2, lbuf);

    // ---- layer 3 ----
    k_gemm_mfma<KCLS, 48><<<gx, blk, 0, stream>>>(lbuf, W3, hbuf, NN);
    k_gather_lsm<<<(NN + 3) / 4, blk, 0, stream>>>(hbuf, rowptr, col, dinv, b3, out);
}

// Round 8
// 391.893 us; speedup vs baseline: 17.1398x; 1.2503x over previous
//
#include <hip/hip_runtime.h>
#include <math.h>

#define NN 100000
#define KHID 128
#define KCLS 40
#define LN_EPS 1e-5f
#define NBKT ((NN + 255) >> 8)     // 391 buckets of 256 dst nodes
#define PCHUNK 4096                // edges per partition workgroup
#define BSTRIDE 5120               // slack bucket capacity (mean 4093, +16 sigma)

typedef unsigned short bfu;
typedef __attribute__((ext_vector_type(8))) short short8;
typedef __attribute__((ext_vector_type(4))) float floatx4;

// float -> bf16 (RNE)
__device__ __forceinline__ bfu f2b(float f) {
    unsigned u = __float_as_uint(f);
    u += 0x7fffu + ((u >> 16) & 1u);
    return (bfu)(u >> 16);
}
__device__ __forceinline__ unsigned pack2(float a, float b) {
    return (unsigned)f2b(a) | ((unsigned)f2b(b) << 16);
}
// 8 bf16 in a uint4: unpack + FMA into a[8]
__device__ __forceinline__ void fma8(uint4 v, float w, float* a) {
    a[0] += w * __uint_as_float(v.x << 16);
    a[1] += w * __uint_as_float(v.x & 0xffff0000u);
    a[2] += w * __uint_as_float(v.y << 16);
    a[3] += w * __uint_as_float(v.y & 0xffff0000u);
    a[4] += w * __uint_as_float(v.z << 16);
    a[5] += w * __uint_as_float(v.z & 0xffff0000u);
    a[6] += w * __uint_as_float(v.w << 16);
    a[7] += w * __uint_as_float(v.w & 0xffff0000u);
}

// ======================= CSR build (3 kernels, no global scan) =======================
__global__ __launch_bounds__(256) void k_binit(int* __restrict__ btail) {
    int b = blockIdx.x * 256 + threadIdx.x;
    if (b < NBKT) btail[b] = b * BSTRIDE;
}

// partition edges into slack dst-buckets; ebuf[pos] = (dst&255)<<20 | src
__global__ __launch_bounds__(256) void k_part(const int* __restrict__ srcA,
                                              const int* __restrict__ dstA,
                                              int* __restrict__ btail,
                                              int* __restrict__ ebuf, int E) {
    __shared__ int hist[NBKT];
    int tid = threadIdx.x;
    int base = blockIdx.x * PCHUNK;
    int sreg[PCHUNK / 256], dreg[PCHUNK / 256];

    for (int k = tid; k < NBKT; k += 256) hist[k] = 0;
    __syncthreads();
#pragma unroll
    for (int j = 0; j < PCHUNK / 256; j++) {
        int e = base + j * 256 + tid;
        if (e < E) {
            sreg[j] = srcA[e];
            int d = dstA[e];
            dreg[j] = d;
            atomicAdd(&hist[d >> 8], 1);
        } else dreg[j] = -1;
    }
    __syncthreads();
    for (int k = tid; k < NBKT; k += 256)
        hist[k] = atomicAdd(&btail[k], hist[k]);   // hist -> global cursor base
    __syncthreads();
#pragma unroll
    for (int j = 0; j < PCHUNK / 256; j++) {
        int d = dreg[j];
        if (d >= 0) {
            int pos = atomicAdd(&hist[d >> 8], 1);
            ebuf[pos] = ((d & 255) << 20) | sreg[j];
        }
    }
}

// per bucket: LDS count -> LDS scan -> rr/dinv/sorted col (all local, no global atomics)
__global__ __launch_bounds__(256) void k_csr(const int* __restrict__ ebuf,
                                             const int* __restrict__ btail,
                                             int2* __restrict__ rr,
                                             int* __restrict__ col,
                                             float* __restrict__ dinv) {
    __shared__ int lcnt[256];
    __shared__ int lcur[256];
    __shared__ int wtot[4];
    int b = blockIdx.x, tid = threadIdx.x;
    int basee = b * BSTRIDE;
    int bend  = btail[b];                 // end cursor after k_part
    lcnt[tid] = 0;
    __syncthreads();
    for (int e = basee + tid; e < bend; e += 256)
        atomicAdd(&lcnt[ebuf[e] >> 20], 1);
    __syncthreads();
    int v = lcnt[tid];
    int lane = tid & 63, wv = tid >> 6;
    int s = v;
#pragma unroll
    for (int off = 1; off < 64; off <<= 1) {
        int u = __shfl_up(s, off);
        if (lane >= off) s += u;
    }
    if (lane == 63) wtot[wv] = s;
    __syncthreads();
    int woff = 0;
    for (int w = 0; w < wv; w++) woff += wtot[w];
    int incl = woff + s;                  // inclusive prefix over the 256 local nodes
    int gi = (b << 8) + tid;
    if (gi < NN) {
        rr[gi] = make_int2(basee + incl - v, basee + incl);
        dinv[gi] = rsqrtf((float)(1 + v));
    }
    lcur[tid] = basee + incl - v;
    __syncthreads();
    for (int e = basee + tid; e < bend; e += 256) {
        int p = ebuf[e];
        int pos = atomicAdd(&lcur[p >> 20], 1);
        col[pos] = p & 0xFFFFF;
    }
}

// ===== MFMA GEMM: C[M,KOUT](bf16) = A[M,128] @ W[128,KOUT](f32); A bf16 or f32 ======
template <int KOUT, int NPAD, bool F32A>
__global__ __launch_bounds__(256) void k_gemm_mfma(const void* __restrict__ Av,
                                                   const float* __restrict__ W,
                                                   bfu* __restrict__ C, int M) {
    constexpr int NT = NPAD / 16;
    __shared__ bfu As[128][136];    // [m][k], +8 pad
    __shared__ bfu Ws[NPAD][136];   // [n][k] transposed, +8 pad

    int tid  = threadIdx.x;
    int row0 = blockIdx.x * 128;

    if constexpr (F32A) {
        // fp32 A: 64 KB tile, cvt to bf16 on LDS store (fuses the cast kernel)
        const float* Af = (const float*)Av + (size_t)row0 * 128;
#pragma unroll
        for (int c2 = 0; c2 < 16; c2++) {
            int off = c2 * 1024 + tid * 4;   // float index
            int r   = off >> 7;
            int kk  = off & 127;
            float4 f = (row0 + r < M) ? *(const float4*)(Af + off)
                                      : make_float4(0.f, 0.f, 0.f, 0.f);
            uint2 pv;
            pv.x = pack2(f.x, f.y);
            pv.y = pack2(f.z, f.w);
            *(uint2*)&As[r][kk] = pv;
        }
    } else {
        const char* Ab = (const char*)Av + (size_t)row0 * 256;
#pragma unroll
        for (int c2 = 0; c2 < 8; c2++) {
            int off = c2 * 4096 + tid * 16;  // byte offset in 32 KB tile
            int r   = off >> 8;
            int kb  = off & 255;
            uint4 v = *(const uint4*)(Ab + off);
            *(uint4*)((char*)&As[0][0] + r * 272 + kb) = v;
        }
    }
    // stage W transposed + cvt bf16
    if constexpr (KOUT == 128) {
        int n = tid & 127, kh = (tid >> 7) * 64;
#pragma unroll
        for (int kk = 0; kk < 64; kk += 8) {
            float f[8];
#pragma unroll
            for (int i = 0; i < 8; i++) f[i] = W[(size_t)(kh + kk + i) * 128 + n];
            uint4 v;
            v.x = pack2(f[0], f[1]); v.y = pack2(f[2], f[3]);
            v.z = pack2(f[4], f[5]); v.w = pack2(f[6], f[7]);
            *(uint4*)&Ws[n][kh + kk] = v;
        }
    } else {
        int n = tid & 63, kh = (tid >> 6) * 32;
        if (n < NPAD) {
#pragma unroll
            for (int kk = 0; kk < 32; kk += 8) {
                float f[8];
#pragma unroll
                for (int i = 0; i < 8; i++)
                    f[i] = (n < KOUT) ? W[(size_t)(kh + kk + i) * KOUT + n] : 0.f;
                uint4 v;
                v.x = pack2(f[0], f[1]); v.y = pack2(f[2], f[3]);
                v.z = pack2(f[4], f[5]); v.w = pack2(f[6], f[7]);
                *(uint4*)&Ws[n][kh + kk] = v;
            }
        }
    }
    __syncthreads();

    int w = tid >> 6, lane = tid & 63;
    int quad = lane >> 4, mrow = lane & 15;

    floatx4 acc[2][NT];
#pragma unroll
    for (int mt = 0; mt < 2; mt++)
#pragma unroll
        for (int nt = 0; nt < NT; nt++) acc[mt][nt] = (floatx4){0.f, 0.f, 0.f, 0.f};

#pragma unroll
    for (int ks = 0; ks < 4; ks++) {
        int ko = ks * 32 + quad * 8;
        short8 af[2];
#pragma unroll
        for (int mt = 0; mt < 2; mt++)
            af[mt] = *(const short8*)&As[16 * (2 * w + mt) + mrow][ko];
#pragma unroll
        for (int nt = 0; nt < NT; nt++) {
            short8 bf = *(const short8*)&Ws[16 * nt + mrow][ko];
#pragma unroll
            for (int mt = 0; mt < 2; mt++)
                acc[mt][nt] = __builtin_amdgcn_mfma_f32_16x16x32_bf16(af[mt], bf, acc[mt][nt], 0, 0, 0);
        }
    }

    // epilogue: C/D layout col=lane&15, row=quad*4+reg
#pragma unroll
    for (int mt = 0; mt < 2; mt++) {
        int rbase = row0 + 16 * (2 * w + mt) + quad * 4;
#pragma unroll
        for (int nt = 0; nt < NT; nt++) {
            int cidx = 16 * nt + mrow;
            if (KOUT != NPAD && cidx >= KOUT) continue;
#pragma unroll
            for (int r = 0; r < 4; r++) {
                int row = rbase + r;
                if (row < M) C[(size_t)row * KOUT + cidx] = f2b(acc[mt][nt][r]);
            }
        }
    }
}

// ======= fused gather + bias + LN + ReLU (K=128), wave/node, 4 edge-slots x 16B =======
__global__ __launch_bounds__(256) void k_gather_ln(const bfu* __restrict__ hb,
                                                   const int2* __restrict__ rr,
                                                   const int* __restrict__ col,
                                                   const float* __restrict__ dinv,
                                                   const float* __restrict__ bias,
                                                   const float* __restrict__ gamma,
                                                   const float* __restrict__ beta,
                                                   bfu* __restrict__ outb) {
    int wave = threadIdx.x >> 6;
    int lane = threadIdx.x & 63;
    int i = blockIdx.x * 4 + wave;
    if (i >= NN) return;
    int2 se = rr[i];
    int start = se.x, end = se.y;
    float di = dinv[i];
    int eq = lane >> 4;          // edge slot 0..3
    int fv = (lane & 15) * 8;    // feature base

    float a[8];
#pragma unroll
    for (int j = 0; j < 8; j++) a[j] = 0.f;
    if (eq == 0) {               // self-loop
        uint4 v = *(const uint4*)(hb + (size_t)i * 128 + fv);
        fma8(v, di * di, a);
    }

    for (int b = start; b < end; b += 64) {
        int n = end - b; if (n > 64) n = 64;
        int c; float wgt;
        if (lane < n) { c = col[b + lane]; wgt = dinv[c] * di; }
        else          { c = i;             wgt = 0.f; }
        int tmax = (n + 3) >> 2;
        int tr = (tmax + 1) & ~1;          // pad slots have wgt=0, e stays < 64
        for (int t = 0; t < tr; t += 2) {
            int e0 = 4 * t + eq, e1 = e0 + 4;
            int c0 = __shfl(c, e0), c1 = __shfl(c, e1);
            float w0 = __shfl(wgt, e0), w1 = __shfl(wgt, e1);
            uint4 v0 = *(const uint4*)(hb + (size_t)c0 * 128 + fv);
            uint4 v1 = *(const uint4*)(hb + (size_t)c1 * 128 + fv);
            fma8(v0, w0, a);
            fma8(v1, w1, a);
        }
    }
    // merge the 4 edge slots
#pragma unroll
    for (int j = 0; j < 8; j++) {
        a[j] += __shfl_xor(a[j], 16);
        a[j] += __shfl_xor(a[j], 32);
    }

    float4 bb0 = *(const float4*)(bias + fv);
    float4 bb1 = *(const float4*)(bias + fv + 4);
    float x0 = a[0] + bb0.x, x1 = a[1] + bb0.y, x2 = a[2] + bb0.z, x3 = a[3] + bb0.w;
    float x4 = a[4] + bb1.x, x5 = a[5] + bb1.y, x6 = a[6] + bb1.z, x7 = a[7] + bb1.w;

    float s = x0 + x1 + x2 + x3 + x4 + x5 + x6 + x7;
#pragma unroll
    for (int m = 1; m < 16; m <<= 1) s += __shfl_xor(s, m);   // 16 groups -> full sum
    float mu = s * (1.f / 128.f);
    float d0 = x0 - mu, d1 = x1 - mu, d2 = x2 - mu, d3 = x3 - mu;
    float d4 = x4 - mu, d5 = x5 - mu, d6 = x6 - mu, d7 = x7 - mu;
    float vs = d0*d0 + d1*d1 + d2*d2 + d3*d3 + d4*d4 + d5*d5 + d6*d6 + d7*d7;
#pragma unroll
    for (int m = 1; m < 16; m <<= 1) vs += __shfl_xor(vs, m);
    float inv = rsqrtf(vs * (1.f / 128.f) + LN_EPS);
    if (eq == 0) {
        float4 gg0 = *(const float4*)(gamma + fv);
        float4 gg1 = *(const float4*)(gamma + fv + 4);
        float4 ee0 = *(const float4*)(beta + fv);
        float4 ee1 = *(const float4*)(beta + fv + 4);
        uint4 o;
        o.x = pack2(fmaxf(d0 * inv * gg0.x + ee0.x, 0.f), fmaxf(d1 * inv * gg0.y + ee0.y, 0.f));
        o.y = pack2(fmaxf(d2 * inv * gg0.z + ee0.z, 0.f), fmaxf(d3 * inv * gg0.w + ee0.w, 0.f));
        o.z = pack2(fmaxf(d4 * inv * gg1.x + ee1.x, 0.f), fmaxf(d5 * inv * gg1.y + ee1.y, 0.f));
        o.w = pack2(fmaxf(d6 * inv * gg1.z + ee1.z, 0.f), fmaxf(d7 * inv * gg1.w + ee1.w, 0.f));
        *(uint4*)(outb + (size_t)i * 128 + fv) = o;
    }
}

// ===== fused gather + bias + log_softmax (K=40), wave/node, 8 edge-slots x 16B =====
__global__ __launch_bounds__(256) void k_gather_lsm(const bfu* __restrict__ hb,
                                                    const int2* __restrict__ rr,
                                                    const int* __restrict__ col,
                                                    const float* __restrict__ dinv,
                                                    const float* __restrict__ b3,
                                                    float* __restrict__ out) {
    int wave = threadIdx.x >> 6;
    int lane = threadIdx.x & 63;
    int i = blockIdx.x * 4 + wave;
    if (i >= NN) return;
    int2 se = rr[i];
    int start = se.x, end = se.y;
    float di = dinv[i];
    int og = lane >> 3;          // edge slot 0..7
    int fo = (lane & 7) * 8;     // feature base 0..56
    bool act = fo < KCLS;        // 5 of 8 lanes carry features

    float a[8];
#pragma unroll
    for (int j = 0; j < 8; j++) a[j] = 0.f;
    if (og == 0 && act) {        // self-loop (rows are 80 B = 16B-aligned)
        uint4 v = *(const uint4*)(hb + (size_t)i * KCLS + fo);
        fma8(v, di * di, a);
    }

    for (int b = start; b < end; b += 64) {
        int n = end - b; if (n > 64) n = 64;
        int c; float wgt;
        if (lane < n) { c = col[b + lane]; wgt = dinv[c] * di; }
        else          { c = i;             wgt = 0.f; }
        int tmax = (n + 7) >> 3;           // e = 8t+og <= 63 always; pads have wgt=0
        for (int t = 0; t < tmax; t++) {
            int e0 = 8 * t + og;
            int c0 = __shfl(c, e0);
            float w0 = __shfl(wgt, e0);
            if (act) {
                uint4 v0 = *(const uint4*)(hb + (size_t)c0 * KCLS + fo);
                fma8(v0, w0, a);
            }
        }
    }
    // merge the 8 edge slots
#pragma unroll
    for (int j = 0; j < 8; j++) {
        a[j] += __shfl_xor(a[j], 8);
        a[j] += __shfl_xor(a[j], 16);
        a[j] += __shfl_xor(a[j], 32);
    }

    float v[8];
    if (act) {
        float4 b30 = *(const float4*)(b3 + fo);
        float4 b31 = *(const float4*)(b3 + fo + 4);
        v[0] = a[0] + b30.x; v[1] = a[1] + b30.y; v[2] = a[2] + b30.z; v[3] = a[3] + b30.w;
        v[4] = a[4] + b31.x; v[5] = a[5] + b31.y; v[6] = a[6] + b31.z; v[7] = a[7] + b31.w;
    } else {
#pragma unroll
        for (int j = 0; j < 8; j++) v[j] = -INFINITY;
    }
    float lm = v[0];
#pragma unroll
    for (int j = 1; j < 8; j++) lm = fmaxf(lm, v[j]);
#pragma unroll
    for (int m = 1; m < 8; m <<= 1) lm = fmaxf(lm, __shfl_xor(lm, m));  // max over 8-lane group
    float es = 0.f;
    if (act) {
#pragma unroll
        for (int j = 0; j < 8; j++) es += expf(v[j] - lm);
    }
#pragma unroll
    for (int m = 1; m < 8; m <<= 1) es += __shfl_xor(es, m);
    if (og == 0 && act) {
        float ls = lm + logf(es);
        float4 o0 = make_float4(v[0] - ls, v[1] - ls, v[2] - ls, v[3] - ls);
        float4 o1 = make_float4(v[4] - ls, v[5] - ls, v[6] - ls, v[7] - ls);
        *(float4*)(out + (size_t)i * KCLS + fo) = o0;
        *(float4*)(out + (size_t)i * KCLS + fo + 4) = o1;
    }
}

extern "C" void kernel_launch(void* const* d_in, const int* in_sizes, int n_in,
                              void* d_out, int out_size, void* d_ws, size_t ws_size,
                              hipStream_t stream) {
    const float* x   = (const float*)d_in[0];
    const int*   ei  = (const int*)d_in[1];
    const float* W1  = (const float*)d_in[2];
    const float* b1  = (const float*)d_in[3];
    const float* g1  = (const float*)d_in[4];
    const float* be1 = (const float*)d_in[5];
    const float* W2  = (const float*)d_in[6];
    const float* b2  = (const float*)d_in[7];
    const float* g2  = (const float*)d_in[8];
    const float* be2 = (const float*)d_in[9];
    const float* W3  = (const float*)d_in[10];
    const float* b3  = (const float*)d_in[11];
    const int E = in_sizes[1] / 2;
    const int* srcI = ei;
    const int* dstI = ei + E;

    // workspace (float units):
    // [dinv NN][rr 2NN][btail 512][hbuf NN*64][lbuf NN*64][col NBKT*BSTRIDE]
    // ebuf aliases lbuf (dead until layer-1 gather writes it). GEMM A-tile overrun:
    // hbuf->lbuf, lbuf->col (both allocated).
    float* dinv   = (float*)d_ws;
    int2*  rr     = (int2*)((float*)d_ws + NN);
    int*   btail  = (int*)d_ws + 3 * NN;
    bfu*   hbuf   = (bfu*)((float*)d_ws + 3 * NN + 512);
    bfu*   lbuf   = (bfu*)((float*)d_ws + 3 * NN + 512 + (size_t)NN * 64);
    int*   col    = (int*)d_ws + 3 * NN + 512 + (size_t)NN * 128;
    int*   ebuf   = (int*)lbuf;

    float* out = (float*)d_out;
    dim3 blk(256);

    // ---- CSR build (slack buckets, no global scan) ----
    k_binit<<<(NBKT + 255) / 256, blk, 0, stream>>>(btail);
    k_part<<<(E + PCHUNK - 1) / PCHUNK, blk, 0, stream>>>(srcI, dstI, btail, ebuf, E);
    k_csr<<<NBKT, blk, 0, stream>>>(ebuf, btail, rr, col, dinv);

    const int gx = (NN + 127) / 128;   // 782

    // ---- layer 1 (fp32 A, fused cast) ----
    k_gemm_mfma<128, 128, true><<<gx, blk, 0, stream>>>(x, W1, hbuf, NN);
    k_gather_ln<<<(NN + 3) / 4, blk, 0, stream>>>(hbuf, rr, col, dinv, b1, g1, be1, lbuf);

    // ---- layer 2 ----
    k_gemm_mfma<128, 128, false><<<gx, blk, 0, stream>>>(lbuf, W2, hbuf, NN);
    k_gather_ln<<<(NN + 3) / 4, blk, 0, stream>>>(hbuf, rr, col, dinv, b2, g2, be2, lbuf);

    // ---- layer 3 ----
    k_gemm_mfma<KCLS, 48, false><<<gx, blk, 0, stream>>>(lbuf, W3, hbuf, NN);
    k_gather_lsm<<<(NN + 3) / 4, blk, 0, stream>>>(hbuf, rr, col, dinv, b3, out);
}